// Round 8
// baseline (142.789 us; speedup 1.0000x reference)
//
#include <hip/hip_runtime.h>

#define NB 16
#define NH 256
#define NL 4096
#define NN 32

typedef short s8v __attribute__((ext_vector_type(8)));
typedef float f4v __attribute__((ext_vector_type(4)));

__device__ __forceinline__ unsigned short f2bf(float x) {
    unsigned int u = __float_as_uint(x);
    unsigned int r = u + 0x7FFFu + ((u >> 16) & 1u);
    return (unsigned short)(r >> 16);
}
__device__ __forceinline__ float bf2f(unsigned short b) {
    return __uint_as_float(((unsigned int)b) << 16);
}

// ---------- merged precompute: per h: w32 consts, Mp, Em, Tm (+ W->bf16 tail) ----------
// Mp[h][64x32] bf16: rows 2n=Re(w^{31-t}), 2n+1=Im(w^{31-t})
// Em[h][32x64] bf16: Em[j][2n]=Re(c2*w^{j+1}), Em[j][2n+1]=-Im(c2*w^{j+1})
// Tm[h][32x32] bf16: T[j][t]=sum_n Re(c2*w^{j-t}) (j>=t), diag += D
__global__ __launch_bounds__(64) void precompute_kernel(
        const float* __restrict__ log_dt,
        const float* __restrict__ Cr,
        const float* __restrict__ Ci,
        const float* __restrict__ lar,
        const float* __restrict__ aim,
        const float* __restrict__ Dvec,
        float* __restrict__ w32c,
        unsigned short* __restrict__ Mp,
        unsigned short* __restrict__ Em,
        unsigned short* __restrict__ Tm,
        const float* __restrict__ W,
        unsigned short* __restrict__ Wbf) {
    const int h = blockIdx.x;
    const int tid = threadIdx.x;
    __shared__ float sRe[32][33];           // [e][n], padded
    __shared__ float sTd[32];
    __shared__ unsigned short sMp[64 * 32];
    __shared__ unsigned short sEm[32 * 64];

    if (tid < 32) {
        const int n = tid;
        const int idx = h * 32 + n;
        float dt = expf(log_dt[h]);
        float ar = -expf(lar[idx]);
        float ai = aim[idx];
        float dar = ar * dt, dai = ai * dt;
        float er = expf(dar);
        float wr = er * cosf(dai), wi = er * sinf(dai);
        float Er = wr - 1.0f, Ei = wi;
        float den = ar * ar + ai * ai;
        float fr = (Er * ar + Ei * ai) / den;
        float fi = (Ei * ar - Er * ai) / den;
        float cr = Cr[idx], ci = Ci[idx];
        float c2r = 2.0f * (cr * fr - ci * fi);
        float c2i = 2.0f * (cr * fi + ci * fr);
        float e32 = expf(32.0f * dar);
        w32c[h * 64 + 2 * n]     = e32 * cosf(32.0f * dai);
        w32c[h * 64 + 2 * n + 1] = e32 * sinf(32.0f * dai);
        // Mp rows: w^{31-t}
        float pr = 1.0f, pi = 0.0f;
        for (int e = 0; e < 32; ++e) {
            sMp[(2 * n) * 32 + (31 - e)]     = f2bf(pr);
            sMp[(2 * n + 1) * 32 + (31 - e)] = f2bf(pi);
            float npr = pr * wr - pi * wi;
            pi = fmaf(pr, wi, pi * wr);
            pr = npr;
        }
        // g_e = c2*w^e, e=0..32: sRe rows (e<32) + Em rows (e>=1)
        float gr = c2r, gi = c2i;
        for (int e = 0; e <= 32; ++e) {
            if (e < 32) sRe[e][n] = gr;
            if (e >= 1) {
                sEm[(e - 1) * 64 + 2 * n]     = f2bf(gr);
                sEm[(e - 1) * 64 + 2 * n + 1] = f2bf(-gi);
            }
            float ngr = gr * wr - gi * wi;
            gi = fmaf(gr, wi, gi * wr);
            gr = ngr;
        }
    }
    __syncthreads();
    if (tid < 32) {
        float a = 0.0f;
        #pragma unroll
        for (int n = 0; n < 32; ++n) a += sRe[tid][n];
        sTd[tid] = a;
    }
    __syncthreads();
    const float dh = Dvec[h];
    unsigned short* tmh = Tm + h * 1024;
    for (int i = 0; i < 16; ++i) {
        int idx = tid * 16 + i;
        int j = idx >> 5, tt = idx & 31;
        float v = (j >= tt) ? sTd[j - tt] : 0.0f;
        if (j == tt) v += dh;
        tmh[idx] = f2bf(v);
    }
    // coalesced stores of Mp/Em (256 uint4 each, 4 per thread)
    uint4* mp4 = (uint4*)(Mp + h * 2048);
    uint4* em4 = (uint4*)(Em + h * 2048);
    const uint4* smp4 = (const uint4*)sMp;
    const uint4* sem4 = (const uint4*)sEm;
    #pragma unroll
    for (int k = 0; k < 4; ++k) {
        mp4[k * 64 + tid] = smp4[k * 64 + tid];
        em4[k * 64 + tid] = sem4[k * 64 + tid];
    }
    // W -> bf16 conversion tail (grid-stride: 32768 float4 over 16384 threads)
    const int gidx = h * 64 + tid;
    #pragma unroll
    for (int k = 0; k < 2; ++k) {
        int i = gidx + k * (NH * 64);
        float4 v = ((const float4*)W)[i];
        ushort4 o;
        o.x = f2bf(v.x); o.y = f2bf(v.y); o.z = f2bf(v.z); o.w = f2bf(v.w);
        ((ushort4*)Wbf)[i] = o;
    }
}

// ---------- MFMA chunked scan: one block per (b,h), 4 waves (unchanged) ----------
__global__ __launch_bounds__(256) void scan_mfma_kernel(
        const float* __restrict__ u,
        const float* __restrict__ w32c,
        const unsigned short* __restrict__ Mp,
        const unsigned short* __restrict__ Tm,
        const unsigned short* __restrict__ Em,
        unsigned short* __restrict__ ybf) {
    const int bh = blockIdx.x;
    const int h = bh & (NH - 1);
    const int tid = threadIdx.x;
    const int lane = tid & 63;
    const int wv = tid >> 6;
    const int g = lane >> 4, c = lane & 15;

    __shared__ __align__(16) char arena[26624];
    unsigned short* u_bf = (unsigned short*)arena;            // [4096] bf16, 8192 B
    unsigned int*   ldsP = (unsigned int*)(arena + 8192);     // [128][36] u32, 18432 B

    {
        const float4* up = (const float4*)(u + (size_t)bh * NL + tid * 16);
        float4 a = up[0], b4 = up[1], c4 = up[2], d4 = up[3];
        union { unsigned short us[16]; uint4 q[2]; } pk;
        pk.us[0]=f2bf(a.x); pk.us[1]=f2bf(a.y); pk.us[2]=f2bf(a.z); pk.us[3]=f2bf(a.w);
        pk.us[4]=f2bf(b4.x); pk.us[5]=f2bf(b4.y); pk.us[6]=f2bf(b4.z); pk.us[7]=f2bf(b4.w);
        pk.us[8]=f2bf(c4.x); pk.us[9]=f2bf(c4.y); pk.us[10]=f2bf(c4.z); pk.us[11]=f2bf(c4.w);
        pk.us[12]=f2bf(d4.x); pk.us[13]=f2bf(d4.y); pk.us[14]=f2bf(d4.z); pk.us[15]=f2bf(d4.w);
        uint4* dst = (uint4*)(u_bf + tid * 16);
        dst[0] = pk.q[0];
        dst[1] = pk.q[1];
    }
    __syncthreads();

    s8v bu[2];
    #pragma unroll
    for (int ntl = 0; ntl < 2; ++ntl)
        bu[ntl] = *(const s8v*)(u_bf + ((2 * wv + ntl) * 16 + c) * 32 + g * 8);

    const unsigned short* mph = Mp + h * 2048;
    f4v p1[4][2];
    #pragma unroll
    for (int mt = 0; mt < 4; ++mt) {
        s8v am = *(const s8v*)(mph + (mt * 16 + c) * 32 + g * 8);
        p1[mt][0] = (f4v){0.f,0.f,0.f,0.f};
        p1[mt][1] = (f4v){0.f,0.f,0.f,0.f};
        p1[mt][0] = __builtin_amdgcn_mfma_f32_16x16x32_bf16(am, bu[0], p1[mt][0], 0,0,0);
        p1[mt][1] = __builtin_amdgcn_mfma_f32_16x16x32_bf16(am, bu[1], p1[mt][1], 0,0,0);
    }
    #pragma unroll
    for (int mt = 0; mt < 4; ++mt)
        #pragma unroll
        for (int ntl = 0; ntl < 2; ++ntl) {
            const int chunk = (2 * wv + ntl) * 16 + c;
            f4v v = p1[mt][ntl];
            unsigned int lo = (unsigned int)f2bf(v[0]) | ((unsigned int)f2bf(v[1]) << 16);
            unsigned int hi = (unsigned int)f2bf(v[2]) | ((unsigned int)f2bf(v[3]) << 16);
            *(uint2*)&ldsP[chunk * 36 + mt * 8 + 2 * g] = make_uint2(lo, hi);
        }
    __syncthreads();

    if (tid < 64) {
        const int n = lane & 31, seg = lane >> 5;
        const float wr = w32c[h * 64 + 2 * n], wi = w32c[h * 64 + 2 * n + 1];
        float sr = 0.f, si = 0.f;
        const int base = seg * 64;
        for (int t = 0; t < 64; ++t) {
            const int chunk = base + t;
            unsigned int pv = ldsP[chunk * 36 + n];
            ldsP[chunk * 36 + n] =
                (unsigned int)f2bf(sr) | ((unsigned int)f2bf(si) << 16);
            float Pr = bf2f((unsigned short)(pv & 0xFFFF));
            float Pi = bf2f((unsigned short)(pv >> 16));
            float nsr = fmaf(wr, sr, fmaf(-wi, si, Pr));
            float nsi = fmaf(wr, si, fmaf(wi, sr, Pi));
            sr = nsr; si = nsi;
        }
        float tr = __shfl(sr, n, 64);
        float ti = __shfl(si, n, 64);
        if (seg == 1) {
            float gr = tr, gi = ti;
            for (int t = 0; t < 64; ++t) {
                const int chunk = 64 + t;
                unsigned int sv = ldsP[chunk * 36 + n];
                float fr2 = bf2f((unsigned short)(sv & 0xFFFF)) + gr;
                float fi2 = bf2f((unsigned short)(sv >> 16)) + gi;
                ldsP[chunk * 36 + n] =
                    (unsigned int)f2bf(fr2) | ((unsigned int)f2bf(fi2) << 16);
                float ngr = wr * gr - wi * gi;
                float ngi = fmaf(wr, gi, wi * gr);
                gr = ngr; gi = ngi;
            }
        }
    }
    __syncthreads();

    const unsigned short* tmh = Tm + h * 1024;
    const unsigned short* emh = Em + h * 2048;
    const unsigned short* sbase = (const unsigned short*)ldsP;
    f4v a2[2][2];
    #pragma unroll
    for (int mt = 0; mt < 2; ++mt) {
        a2[mt][0] = (f4v){0.f,0.f,0.f,0.f};
        a2[mt][1] = (f4v){0.f,0.f,0.f,0.f};
        s8v at = *(const s8v*)(tmh + (mt * 16 + c) * 32 + g * 8);
        a2[mt][0] = __builtin_amdgcn_mfma_f32_16x16x32_bf16(at, bu[0], a2[mt][0], 0,0,0);
        a2[mt][1] = __builtin_amdgcn_mfma_f32_16x16x32_bf16(at, bu[1], a2[mt][1], 0,0,0);
    }
    #pragma unroll
    for (int ksub = 0; ksub < 2; ++ksub) {
        s8v bs[2];
        #pragma unroll
        for (int ntl = 0; ntl < 2; ++ntl) {
            const int chunk = (2 * wv + ntl) * 16 + c;
            bs[ntl] = *(const s8v*)(sbase + chunk * 72 + ksub * 32 + g * 8);
        }
        #pragma unroll
        for (int mt = 0; mt < 2; ++mt) {
            s8v ae = *(const s8v*)(emh + (mt * 16 + c) * 64 + ksub * 32 + g * 8);
            a2[mt][0] = __builtin_amdgcn_mfma_f32_16x16x32_bf16(ae, bs[0], a2[mt][0], 0,0,0);
            a2[mt][1] = __builtin_amdgcn_mfma_f32_16x16x32_bf16(ae, bs[1], a2[mt][1], 0,0,0);
        }
    }

    unsigned short* yrow = ybf + (size_t)bh * NL;
    #pragma unroll
    for (int mt = 0; mt < 2; ++mt)
        #pragma unroll
        for (int ntl = 0; ntl < 2; ++ntl) {
            const int chunk = (2 * wv + ntl) * 16 + c;
            f4v v = a2[mt][ntl];
            unsigned short gs[4];
            #pragma unroll
            for (int r = 0; r < 4; ++r) {
                float x = v[r];
                gs[r] = f2bf(0.5f * x * (1.0f + erff(x * 0.70710678118654752f)));
            }
            unsigned int lo = (unsigned int)gs[0] | ((unsigned int)gs[1] << 16);
            unsigned int hi = (unsigned int)gs[2] | ((unsigned int)gs[3] << 16);
            *(uint2*)(yrow + chunk * 32 + mt * 16 + 4 * g) = make_uint2(lo, hi);
        }
}

// ---------------- MFMA GEMM + GLU, register-double-buffered staging ----------------
// Grid 2048 blocks; __launch_bounds__(256,4) caps VGPR at 128 -> 4 blocks/CU
// -> exactly 2 residency rounds (no ragged tail). y(ks+1) global loads are
// issued right after packing y(ks), so W-loads + barrier + ds_read + 32 MFMA
// (~800+ cyc) cover their latency (T14 split).
__global__ __launch_bounds__(256, 4) void gemm_glu_mfma(
        const unsigned short* __restrict__ ybf,
        const unsigned short* __restrict__ Wbf,
        const float* __restrict__ bo,
        float* __restrict__ out) {
    const int l0  = blockIdx.x * 128;
    const int ho0 = blockIdx.y * 64;
    const int b   = blockIdx.z;
    const int tid = threadIdx.x;
    const int lane = tid & 63;
    const int wid  = tid >> 6;
    const int wm = wid >> 1, wn = wid & 1;
    const int g = lane >> 4, c = lane & 15;

    __shared__ __align__(16) unsigned int ldsY[128 * 36];

    f4v acc[4][4];
    #pragma unroll
    for (int m = 0; m < 4; ++m)
        #pragma unroll
        for (int n = 0; n < 4; ++n)
            acc[m][n] = (f4v){0.f, 0.f, 0.f, 0.f};

    const int kp  = tid & 31;
    const int lc0 = tid >> 5;
    const unsigned short* ysrc = ybf + ((size_t)b * NH + 2 * kp) * NL + l0;

    int wrow[4];
    wrow[0] = ho0 + wm * 32 + c;
    wrow[1] = wrow[0] + 16;
    wrow[2] = wrow[0] + 256;
    wrow[3] = wrow[1] + 256;

    // prologue: y(0) into the prefetch buffer
    uint4 nx0 = *(const uint4*)(ysrc + lc0 * 8);
    uint4 nx1 = *(const uint4*)(ysrc + NL + lc0 * 8);
    uint4 nx2 = *(const uint4*)(ysrc + (lc0 + 8) * 8);
    uint4 nx3 = *(const uint4*)(ysrc + NL + (lc0 + 8) * 8);

    #pragma unroll
    for (int ks = 0; ks < 4; ++ks) {
        uint4 ya0 = nx0, yb0 = nx1, ya1 = nx2, yb1 = nx3;

        __syncthreads();  // previous iteration's ds_reads complete
        // pack-transpose current chunk into LDS
        {
            typedef unsigned short u8h __attribute__((ext_vector_type(8)));
            u8h ah = *(const u8h*)&ya0, bh = *(const u8h*)&yb0;
            #pragma unroll
            for (int j = 0; j < 8; ++j)
                ldsY[(lc0 * 8 + j) * 36 + kp] =
                    (unsigned int)ah[j] | ((unsigned int)bh[j] << 16);
            u8h ah1 = *(const u8h*)&ya1, bh1 = *(const u8h*)&yb1;
            #pragma unroll
            for (int j = 0; j < 8; ++j)
                ldsY[((lc0 + 8) * 8 + j) * 36 + kp] =
                    (unsigned int)ah1[j] | ((unsigned int)bh1[j] << 16);
        }
        // issue next chunk's global loads NOW (latency hides under MFMA phase)
        if (ks < 3) {
            const unsigned short* pn = ysrc + (size_t)(ks + 1) * 64 * NL;
            nx0 = *(const uint4*)(pn + lc0 * 8);
            nx1 = *(const uint4*)(pn + NL + lc0 * 8);
            nx2 = *(const uint4*)(pn + (lc0 + 8) * 8);
            nx3 = *(const uint4*)(pn + NL + (lc0 + 8) * 8);
        }
        // W fragments (L2-resident)
        s8v afr[2][4];
        #pragma unroll
        for (int m = 0; m < 4; ++m) {
            const unsigned short* wsrc = Wbf + wrow[m] * NH + ks * 64 + g * 8;
            afr[0][m] = *(const s8v*)(wsrc);
            afr[1][m] = *(const s8v*)(wsrc + 32);
        }
        __syncthreads();  // LDS tile visible

        #pragma unroll
        for (int ksub = 0; ksub < 2; ++ksub) {
            s8v bfr[4];
            #pragma unroll
            for (int n = 0; n < 4; ++n) {
                const int row = wn * 64 + n * 16 + c;
                bfr[n] = *(const s8v*)&ldsY[row * 36 + ksub * 16 + g * 4];
            }
            #pragma unroll
            for (int m = 0; m < 4; ++m)
                #pragma unroll
                for (int n = 0; n < 4; ++n)
                    acc[m][n] = __builtin_amdgcn_mfma_f32_16x16x32_bf16(
                        afr[ksub][m], bfr[n], acc[m][n], 0, 0, 0);
        }
    }

    #pragma unroll
    for (int m = 0; m < 2; ++m) {
        const int o0 = ho0 + wm * 32 + m * 16 + g * 4;
        float4 ba = *(const float4*)(bo + o0);
        float4 bb = *(const float4*)(bo + NH + o0);
        const float baj[4] = {ba.x, ba.y, ba.z, ba.w};
        const float bbj[4] = {bb.x, bb.y, bb.z, bb.w};
        #pragma unroll
        for (int j = 0; j < 4; ++j) {
            float* orow = out + ((size_t)(b * NH + o0 + j)) * NL + l0 + wn * 64 + c;
            #pragma unroll
            for (int n = 0; n < 4; ++n) {
                float za = acc[m][n][j] + baj[j];
                float zb = acc[m + 2][n][j] + bbj[j];
                orow[n * 16] = za / (1.0f + expf(-zb));
            }
        }
    }
}

extern "C" void kernel_launch(void* const* d_in, const int* in_sizes, int n_in,
                              void* d_out, int out_size, void* d_ws, size_t ws_size,
                              hipStream_t stream) {
    (void)in_sizes; (void)n_in; (void)out_size; (void)ws_size;
    const float* u      = (const float*)d_in[0];
    const float* log_dt = (const float*)d_in[1];
    const float* Cr     = (const float*)d_in[2];
    const float* Ci     = (const float*)d_in[3];
    const float* lar    = (const float*)d_in[4];
    const float* aim    = (const float*)d_in[5];
    const float* Dvec   = (const float*)d_in[6];
    const float* W      = (const float*)d_in[7];
    const float* bo     = (const float*)d_in[8];
    float* out = (float*)d_out;

    char* ws = (char*)d_ws;
    float*          w32c = (float*)ws;                          // 64 KB
    unsigned short* Mp   = (unsigned short*)(ws + 65536);       // 1 MB
    unsigned short* Em   = (unsigned short*)(ws + 1114112);     // 1 MB
    unsigned short* Tm   = (unsigned short*)(ws + 2162688);     // 512 KB
    unsigned short* Wbf  = (unsigned short*)(ws + 2686976);     // 256 KB
    unsigned short* ybf  = (unsigned short*)(ws + 2949120);     // 32 MB

    precompute_kernel<<<dim3(NH), dim3(64), 0, stream>>>(
        log_dt, Cr, Ci, lar, aim, Dvec, w32c, Mp, Em, Tm, W, Wbf);
    scan_mfma_kernel<<<dim3(NB * NH), dim3(256), 0, stream>>>(u, w32c, Mp, Tm, Em, ybf);
    gemm_glu_mfma<<<dim3(NL / 128, NH / 64, NB), dim3(256), 0, stream>>>(ybf, Wbf, bo, out);
}

// Round 9
// 113.762 us; speedup vs baseline: 1.2552x; 1.2552x over previous
//
#include <hip/hip_runtime.h>

#define NB 16
#define NH 256
#define NL 4096
#define NN 32

typedef short s8v __attribute__((ext_vector_type(8)));
typedef float f4v __attribute__((ext_vector_type(4)));

__device__ __forceinline__ unsigned short f2bf(float x) {
    unsigned int u = __float_as_uint(x);
    unsigned int r = u + 0x7FFFu + ((u >> 16) & 1u);
    return (unsigned short)(r >> 16);
}
__device__ __forceinline__ float bf2f(unsigned short b) {
    return __uint_as_float(((unsigned int)b) << 16);
}

// ---------- merged precompute: per h: w32 consts, Mp, Em, Tm (+ W->bf16 tail) ----------
// Mp[h][64x32] bf16: rows 2n=Re(w^{31-t}), 2n+1=Im(w^{31-t})
// Em[h][32x64] bf16: Em[j][2n]=Re(c2*w^{j+1}), Em[j][2n+1]=-Im(c2*w^{j+1})
// Tm[h][32x32] bf16: T[j][t]=sum_n Re(c2*w^{j-t}) (j>=t), diag += D
__global__ __launch_bounds__(64) void precompute_kernel(
        const float* __restrict__ log_dt,
        const float* __restrict__ Cr,
        const float* __restrict__ Ci,
        const float* __restrict__ lar,
        const float* __restrict__ aim,
        const float* __restrict__ Dvec,
        float* __restrict__ w32c,
        unsigned short* __restrict__ Mp,
        unsigned short* __restrict__ Em,
        unsigned short* __restrict__ Tm,
        const float* __restrict__ W,
        unsigned short* __restrict__ Wbf) {
    const int h = blockIdx.x;
    const int tid = threadIdx.x;
    __shared__ float sRe[32][33];           // [e][n], padded
    __shared__ float sTd[32];
    __shared__ unsigned short sMp[64 * 32];
    __shared__ unsigned short sEm[32 * 64];

    if (tid < 32) {
        const int n = tid;
        const int idx = h * 32 + n;
        float dt = expf(log_dt[h]);
        float ar = -expf(lar[idx]);
        float ai = aim[idx];
        float dar = ar * dt, dai = ai * dt;
        float er = expf(dar);
        float wr = er * cosf(dai), wi = er * sinf(dai);
        float Er = wr - 1.0f, Ei = wi;
        float den = ar * ar + ai * ai;
        float fr = (Er * ar + Ei * ai) / den;
        float fi = (Ei * ar - Er * ai) / den;
        float cr = Cr[idx], ci = Ci[idx];
        float c2r = 2.0f * (cr * fr - ci * fi);
        float c2i = 2.0f * (cr * fi + ci * fr);
        float e32 = expf(32.0f * dar);
        w32c[h * 64 + 2 * n]     = e32 * cosf(32.0f * dai);
        w32c[h * 64 + 2 * n + 1] = e32 * sinf(32.0f * dai);
        // Mp rows: w^{31-t}
        float pr = 1.0f, pi = 0.0f;
        for (int e = 0; e < 32; ++e) {
            sMp[(2 * n) * 32 + (31 - e)]     = f2bf(pr);
            sMp[(2 * n + 1) * 32 + (31 - e)] = f2bf(pi);
            float npr = pr * wr - pi * wi;
            pi = fmaf(pr, wi, pi * wr);
            pr = npr;
        }
        // g_e = c2*w^e, e=0..32: sRe rows (e<32) + Em rows (e>=1)
        float gr = c2r, gi = c2i;
        for (int e = 0; e <= 32; ++e) {
            if (e < 32) sRe[e][n] = gr;
            if (e >= 1) {
                sEm[(e - 1) * 64 + 2 * n]     = f2bf(gr);
                sEm[(e - 1) * 64 + 2 * n + 1] = f2bf(-gi);
            }
            float ngr = gr * wr - gi * wi;
            gi = fmaf(gr, wi, gi * wr);
            gr = ngr;
        }
    }
    __syncthreads();
    if (tid < 32) {
        float a = 0.0f;
        #pragma unroll
        for (int n = 0; n < 32; ++n) a += sRe[tid][n];
        sTd[tid] = a;
    }
    __syncthreads();
    const float dh = Dvec[h];
    unsigned short* tmh = Tm + h * 1024;
    for (int i = 0; i < 16; ++i) {
        int idx = tid * 16 + i;
        int j = idx >> 5, tt = idx & 31;
        float v = (j >= tt) ? sTd[j - tt] : 0.0f;
        if (j == tt) v += dh;
        tmh[idx] = f2bf(v);
    }
    // coalesced stores of Mp/Em (256 uint4 each, 4 per thread)
    uint4* mp4 = (uint4*)(Mp + h * 2048);
    uint4* em4 = (uint4*)(Em + h * 2048);
    const uint4* smp4 = (const uint4*)sMp;
    const uint4* sem4 = (const uint4*)sEm;
    #pragma unroll
    for (int k = 0; k < 4; ++k) {
        mp4[k * 64 + tid] = smp4[k * 64 + tid];
        em4[k * 64 + tid] = sem4[k * 64 + tid];
    }
    // W -> bf16 conversion tail (grid-stride: 32768 float4 over 16384 threads)
    const int gidx = h * 64 + tid;
    #pragma unroll
    for (int k = 0; k < 2; ++k) {
        int i = gidx + k * (NH * 64);
        float4 v = ((const float4*)W)[i];
        ushort4 o;
        o.x = f2bf(v.x); o.y = f2bf(v.y); o.z = f2bf(v.z); o.w = f2bf(v.w);
        ((ushort4*)Wbf)[i] = o;
    }
}

// ---------- MFMA chunked scan: one block per (b,h), 4 waves (unchanged) ----------
__global__ __launch_bounds__(256) void scan_mfma_kernel(
        const float* __restrict__ u,
        const float* __restrict__ w32c,
        const unsigned short* __restrict__ Mp,
        const unsigned short* __restrict__ Tm,
        const unsigned short* __restrict__ Em,
        unsigned short* __restrict__ ybf) {
    const int bh = blockIdx.x;
    const int h = bh & (NH - 1);
    const int tid = threadIdx.x;
    const int lane = tid & 63;
    const int wv = tid >> 6;
    const int g = lane >> 4, c = lane & 15;

    __shared__ __align__(16) char arena[26624];
    unsigned short* u_bf = (unsigned short*)arena;            // [4096] bf16, 8192 B
    unsigned int*   ldsP = (unsigned int*)(arena + 8192);     // [128][36] u32, 18432 B

    {
        const float4* up = (const float4*)(u + (size_t)bh * NL + tid * 16);
        float4 a = up[0], b4 = up[1], c4 = up[2], d4 = up[3];
        union { unsigned short us[16]; uint4 q[2]; } pk;
        pk.us[0]=f2bf(a.x); pk.us[1]=f2bf(a.y); pk.us[2]=f2bf(a.z); pk.us[3]=f2bf(a.w);
        pk.us[4]=f2bf(b4.x); pk.us[5]=f2bf(b4.y); pk.us[6]=f2bf(b4.z); pk.us[7]=f2bf(b4.w);
        pk.us[8]=f2bf(c4.x); pk.us[9]=f2bf(c4.y); pk.us[10]=f2bf(c4.z); pk.us[11]=f2bf(c4.w);
        pk.us[12]=f2bf(d4.x); pk.us[13]=f2bf(d4.y); pk.us[14]=f2bf(d4.z); pk.us[15]=f2bf(d4.w);
        uint4* dst = (uint4*)(u_bf + tid * 16);
        dst[0] = pk.q[0];
        dst[1] = pk.q[1];
    }
    __syncthreads();

    s8v bu[2];
    #pragma unroll
    for (int ntl = 0; ntl < 2; ++ntl)
        bu[ntl] = *(const s8v*)(u_bf + ((2 * wv + ntl) * 16 + c) * 32 + g * 8);

    const unsigned short* mph = Mp + h * 2048;
    f4v p1[4][2];
    #pragma unroll
    for (int mt = 0; mt < 4; ++mt) {
        s8v am = *(const s8v*)(mph + (mt * 16 + c) * 32 + g * 8);
        p1[mt][0] = (f4v){0.f,0.f,0.f,0.f};
        p1[mt][1] = (f4v){0.f,0.f,0.f,0.f};
        p1[mt][0] = __builtin_amdgcn_mfma_f32_16x16x32_bf16(am, bu[0], p1[mt][0], 0,0,0);
        p1[mt][1] = __builtin_amdgcn_mfma_f32_16x16x32_bf16(am, bu[1], p1[mt][1], 0,0,0);
    }
    #pragma unroll
    for (int mt = 0; mt < 4; ++mt)
        #pragma unroll
        for (int ntl = 0; ntl < 2; ++ntl) {
            const int chunk = (2 * wv + ntl) * 16 + c;
            f4v v = p1[mt][ntl];
            unsigned int lo = (unsigned int)f2bf(v[0]) | ((unsigned int)f2bf(v[1]) << 16);
            unsigned int hi = (unsigned int)f2bf(v[2]) | ((unsigned int)f2bf(v[3]) << 16);
            *(uint2*)&ldsP[chunk * 36 + mt * 8 + 2 * g] = make_uint2(lo, hi);
        }
    __syncthreads();

    if (tid < 64) {
        const int n = lane & 31, seg = lane >> 5;
        const float wr = w32c[h * 64 + 2 * n], wi = w32c[h * 64 + 2 * n + 1];
        float sr = 0.f, si = 0.f;
        const int base = seg * 64;
        for (int t = 0; t < 64; ++t) {
            const int chunk = base + t;
            unsigned int pv = ldsP[chunk * 36 + n];
            ldsP[chunk * 36 + n] =
                (unsigned int)f2bf(sr) | ((unsigned int)f2bf(si) << 16);
            float Pr = bf2f((unsigned short)(pv & 0xFFFF));
            float Pi = bf2f((unsigned short)(pv >> 16));
            float nsr = fmaf(wr, sr, fmaf(-wi, si, Pr));
            float nsi = fmaf(wr, si, fmaf(wi, sr, Pi));
            sr = nsr; si = nsi;
        }
        float tr = __shfl(sr, n, 64);
        float ti = __shfl(si, n, 64);
        if (seg == 1) {
            float gr = tr, gi = ti;
            for (int t = 0; t < 64; ++t) {
                const int chunk = 64 + t;
                unsigned int sv = ldsP[chunk * 36 + n];
                float fr2 = bf2f((unsigned short)(sv & 0xFFFF)) + gr;
                float fi2 = bf2f((unsigned short)(sv >> 16)) + gi;
                ldsP[chunk * 36 + n] =
                    (unsigned int)f2bf(fr2) | ((unsigned int)f2bf(fi2) << 16);
                float ngr = wr * gr - wi * gi;
                float ngi = fmaf(wr, gi, wi * gr);
                gr = ngr; gi = ngi;
            }
        }
    }
    __syncthreads();

    const unsigned short* tmh = Tm + h * 1024;
    const unsigned short* emh = Em + h * 2048;
    const unsigned short* sbase = (const unsigned short*)ldsP;
    f4v a2[2][2];
    #pragma unroll
    for (int mt = 0; mt < 2; ++mt) {
        a2[mt][0] = (f4v){0.f,0.f,0.f,0.f};
        a2[mt][1] = (f4v){0.f,0.f,0.f,0.f};
        s8v at = *(const s8v*)(tmh + (mt * 16 + c) * 32 + g * 8);
        a2[mt][0] = __builtin_amdgcn_mfma_f32_16x16x32_bf16(at, bu[0], a2[mt][0], 0,0,0);
        a2[mt][1] = __builtin_amdgcn_mfma_f32_16x16x32_bf16(at, bu[1], a2[mt][1], 0,0,0);
    }
    #pragma unroll
    for (int ksub = 0; ksub < 2; ++ksub) {
        s8v bs[2];
        #pragma unroll
        for (int ntl = 0; ntl < 2; ++ntl) {
            const int chunk = (2 * wv + ntl) * 16 + c;
            bs[ntl] = *(const s8v*)(sbase + chunk * 72 + ksub * 32 + g * 8);
        }
        #pragma unroll
        for (int mt = 0; mt < 2; ++mt) {
            s8v ae = *(const s8v*)(emh + (mt * 16 + c) * 64 + ksub * 32 + g * 8);
            a2[mt][0] = __builtin_amdgcn_mfma_f32_16x16x32_bf16(ae, bs[0], a2[mt][0], 0,0,0);
            a2[mt][1] = __builtin_amdgcn_mfma_f32_16x16x32_bf16(ae, bs[1], a2[mt][1], 0,0,0);
        }
    }

    unsigned short* yrow = ybf + (size_t)bh * NL;
    #pragma unroll
    for (int mt = 0; mt < 2; ++mt)
        #pragma unroll
        for (int ntl = 0; ntl < 2; ++ntl) {
            const int chunk = (2 * wv + ntl) * 16 + c;
            f4v v = a2[mt][ntl];
            unsigned short gs[4];
            #pragma unroll
            for (int r = 0; r < 4; ++r) {
                float x = v[r];
                gs[r] = f2bf(0.5f * x * (1.0f + erff(x * 0.70710678118654752f)));
            }
            unsigned int lo = (unsigned int)gs[0] | ((unsigned int)gs[1] << 16);
            unsigned int hi = (unsigned int)gs[2] | ((unsigned int)gs[3] << 16);
            *(uint2*)(yrow + chunk * 32 + mt * 16 + 4 * g) = make_uint2(lo, hi);
        }
}

// ---------------- MFMA GEMM + GLU, register-double-buffered staging ----------------
// NO min-waves launch_bounds (R8 lesson: (256,4) clamped VGPR to 64 -> acc spilled
// -> +240MB scratch HBM traffic). Natural allocation ~108 VGPR, no spill.
__global__ __launch_bounds__(256) void gemm_glu_mfma(
        const unsigned short* __restrict__ ybf,
        const unsigned short* __restrict__ Wbf,
        const float* __restrict__ bo,
        float* __restrict__ out) {
    const int l0  = blockIdx.x * 128;
    const int ho0 = blockIdx.y * 64;
    const int b   = blockIdx.z;
    const int tid = threadIdx.x;
    const int lane = tid & 63;
    const int wid  = tid >> 6;
    const int wm = wid >> 1, wn = wid & 1;
    const int g = lane >> 4, c = lane & 15;

    __shared__ __align__(16) unsigned int ldsY[128 * 36];

    f4v acc[4][4];
    #pragma unroll
    for (int m = 0; m < 4; ++m)
        #pragma unroll
        for (int n = 0; n < 4; ++n)
            acc[m][n] = (f4v){0.f, 0.f, 0.f, 0.f};

    const int kp  = tid & 31;
    const int lc0 = tid >> 5;
    const unsigned short* ysrc = ybf + ((size_t)b * NH + 2 * kp) * NL + l0;

    int wrow[4];
    wrow[0] = ho0 + wm * 32 + c;
    wrow[1] = wrow[0] + 16;
    wrow[2] = wrow[0] + 256;
    wrow[3] = wrow[1] + 256;

    // prologue: y(0) into the prefetch buffer
    uint4 nx0 = *(const uint4*)(ysrc + lc0 * 8);
    uint4 nx1 = *(const uint4*)(ysrc + NL + lc0 * 8);
    uint4 nx2 = *(const uint4*)(ysrc + (lc0 + 8) * 8);
    uint4 nx3 = *(const uint4*)(ysrc + NL + (lc0 + 8) * 8);

    #pragma unroll
    for (int ks = 0; ks < 4; ++ks) {
        uint4 ya0 = nx0, yb0 = nx1, ya1 = nx2, yb1 = nx3;

        __syncthreads();  // previous iteration's ds_reads complete
        // pack-transpose current chunk into LDS
        {
            typedef unsigned short u8h __attribute__((ext_vector_type(8)));
            u8h ah = *(const u8h*)&ya0, bh = *(const u8h*)&yb0;
            #pragma unroll
            for (int j = 0; j < 8; ++j)
                ldsY[(lc0 * 8 + j) * 36 + kp] =
                    (unsigned int)ah[j] | ((unsigned int)bh[j] << 16);
            u8h ah1 = *(const u8h*)&ya1, bh1 = *(const u8h*)&yb1;
            #pragma unroll
            for (int j = 0; j < 8; ++j)
                ldsY[((lc0 + 8) * 8 + j) * 36 + kp] =
                    (unsigned int)ah1[j] | ((unsigned int)bh1[j] << 16);
        }
        // issue next chunk's global loads NOW (latency hides under MFMA phase)
        if (ks < 3) {
            const unsigned short* pn = ysrc + (size_t)(ks + 1) * 64 * NL;
            nx0 = *(const uint4*)(pn + lc0 * 8);
            nx1 = *(const uint4*)(pn + NL + lc0 * 8);
            nx2 = *(const uint4*)(pn + (lc0 + 8) * 8);
            nx3 = *(const uint4*)(pn + NL + (lc0 + 8) * 8);
        }
        // W fragments (L2-resident)
        s8v afr[2][4];
        #pragma unroll
        for (int m = 0; m < 4; ++m) {
            const unsigned short* wsrc = Wbf + wrow[m] * NH + ks * 64 + g * 8;
            afr[0][m] = *(const s8v*)(wsrc);
            afr[1][m] = *(const s8v*)(wsrc + 32);
        }
        __syncthreads();  // LDS tile visible

        #pragma unroll
        for (int ksub = 0; ksub < 2; ++ksub) {
            s8v bfr[4];
            #pragma unroll
            for (int n = 0; n < 4; ++n) {
                const int row = wn * 64 + n * 16 + c;
                bfr[n] = *(const s8v*)&ldsY[row * 36 + ksub * 16 + g * 4];
            }
            #pragma unroll
            for (int m = 0; m < 4; ++m)
                #pragma unroll
                for (int n = 0; n < 4; ++n)
                    acc[m][n] = __builtin_amdgcn_mfma_f32_16x16x32_bf16(
                        afr[ksub][m], bfr[n], acc[m][n], 0, 0, 0);
        }
    }

    #pragma unroll
    for (int m = 0; m < 2; ++m) {
        const int o0 = ho0 + wm * 32 + m * 16 + g * 4;
        float4 ba = *(const float4*)(bo + o0);
        float4 bb = *(const float4*)(bo + NH + o0);
        const float baj[4] = {ba.x, ba.y, ba.z, ba.w};
        const float bbj[4] = {bb.x, bb.y, bb.z, bb.w};
        #pragma unroll
        for (int j = 0; j < 4; ++j) {
            float* orow = out + ((size_t)(b * NH + o0 + j)) * NL + l0 + wn * 64 + c;
            #pragma unroll
            for (int n = 0; n < 4; ++n) {
                float za = acc[m][n][j] + baj[j];
                float zb = acc[m + 2][n][j] + bbj[j];
                orow[n * 16] = za / (1.0f + expf(-zb));
            }
        }
    }
}

extern "C" void kernel_launch(void* const* d_in, const int* in_sizes, int n_in,
                              void* d_out, int out_size, void* d_ws, size_t ws_size,
                              hipStream_t stream) {
    (void)in_sizes; (void)n_in; (void)out_size; (void)ws_size;
    const float* u      = (const float*)d_in[0];
    const float* log_dt = (const float*)d_in[1];
    const float* Cr     = (const float*)d_in[2];
    const float* Ci     = (const float*)d_in[3];
    const float* lar    = (const float*)d_in[4];
    const float* aim    = (const float*)d_in[5];
    const float* Dvec   = (const float*)d_in[6];
    const float* W      = (const float*)d_in[7];
    const float* bo     = (const float*)d_in[8];
    float* out = (float*)d_out;

    char* ws = (char*)d_ws;
    float*          w32c = (float*)ws;                          // 64 KB
    unsigned short* Mp   = (unsigned short*)(ws + 65536);       // 1 MB
    unsigned short* Em   = (unsigned short*)(ws + 1114112);     // 1 MB
    unsigned short* Tm   = (unsigned short*)(ws + 2162688);     // 512 KB
    unsigned short* Wbf  = (unsigned short*)(ws + 2686976);     // 256 KB
    unsigned short* ybf  = (unsigned short*)(ws + 2949120);     // 32 MB

    precompute_kernel<<<dim3(NH), dim3(64), 0, stream>>>(
        log_dt, Cr, Ci, lar, aim, Dvec, w32c, Mp, Em, Tm, W, Wbf);
    scan_mfma_kernel<<<dim3(NB * NH), dim3(256), 0, stream>>>(u, w32c, Mp, Tm, Em, ybf);
    gemm_glu_mfma<<<dim3(NL / 128, NH / 64, NB), dim3(256), 0, stream>>>(ybf, Wbf, bo, out);
}

// Round 10
// 110.675 us; speedup vs baseline: 1.2902x; 1.0279x over previous
//
#include <hip/hip_runtime.h>

#define NB 16
#define NH 256
#define NL 4096
#define NN 32

typedef short s8v __attribute__((ext_vector_type(8)));
typedef float f4v __attribute__((ext_vector_type(4)));
typedef unsigned short u8h __attribute__((ext_vector_type(8)));

__device__ __forceinline__ unsigned short f2bf(float x) {
    unsigned int u = __float_as_uint(x);
    unsigned int r = u + 0x7FFFu + ((u >> 16) & 1u);
    return (unsigned short)(r >> 16);
}
__device__ __forceinline__ float bf2f(unsigned short b) {
    return __uint_as_float(((unsigned int)b) << 16);
}

// ---------- merged precompute: per h: w32 consts, Mp, Em, Tm (+ W->bf16 tail) ----------
__global__ __launch_bounds__(64) void precompute_kernel(
        const float* __restrict__ log_dt,
        const float* __restrict__ Cr,
        const float* __restrict__ Ci,
        const float* __restrict__ lar,
        const float* __restrict__ aim,
        const float* __restrict__ Dvec,
        float* __restrict__ w32c,
        unsigned short* __restrict__ Mp,
        unsigned short* __restrict__ Em,
        unsigned short* __restrict__ Tm,
        const float* __restrict__ W,
        unsigned short* __restrict__ Wbf) {
    const int h = blockIdx.x;
    const int tid = threadIdx.x;
    __shared__ float sRe[32][33];
    __shared__ float sTd[32];
    __shared__ unsigned short sMp[64 * 32];
    __shared__ unsigned short sEm[32 * 64];

    if (tid < 32) {
        const int n = tid;
        const int idx = h * 32 + n;
        float dt = expf(log_dt[h]);
        float ar = -expf(lar[idx]);
        float ai = aim[idx];
        float dar = ar * dt, dai = ai * dt;
        float er = expf(dar);
        float wr = er * cosf(dai), wi = er * sinf(dai);
        float Er = wr - 1.0f, Ei = wi;
        float den = ar * ar + ai * ai;
        float fr = (Er * ar + Ei * ai) / den;
        float fi = (Ei * ar - Er * ai) / den;
        float cr = Cr[idx], ci = Ci[idx];
        float c2r = 2.0f * (cr * fr - ci * fi);
        float c2i = 2.0f * (cr * fi + ci * fr);
        float e32 = expf(32.0f * dar);
        w32c[h * 64 + 2 * n]     = e32 * cosf(32.0f * dai);
        w32c[h * 64 + 2 * n + 1] = e32 * sinf(32.0f * dai);
        float pr = 1.0f, pi = 0.0f;
        for (int e = 0; e < 32; ++e) {
            sMp[(2 * n) * 32 + (31 - e)]     = f2bf(pr);
            sMp[(2 * n + 1) * 32 + (31 - e)] = f2bf(pi);
            float npr = pr * wr - pi * wi;
            pi = fmaf(pr, wi, pi * wr);
            pr = npr;
        }
        float gr = c2r, gi = c2i;
        for (int e = 0; e <= 32; ++e) {
            if (e < 32) sRe[e][n] = gr;
            if (e >= 1) {
                sEm[(e - 1) * 64 + 2 * n]     = f2bf(gr);
                sEm[(e - 1) * 64 + 2 * n + 1] = f2bf(-gi);
            }
            float ngr = gr * wr - gi * wi;
            gi = fmaf(gr, wi, gi * wr);
            gr = ngr;
        }
    }
    __syncthreads();
    if (tid < 32) {
        float a = 0.0f;
        #pragma unroll
        for (int n = 0; n < 32; ++n) a += sRe[tid][n];
        sTd[tid] = a;
    }
    __syncthreads();
    const float dh = Dvec[h];
    unsigned short* tmh = Tm + h * 1024;
    for (int i = 0; i < 16; ++i) {
        int idx = tid * 16 + i;
        int j = idx >> 5, tt = idx & 31;
        float v = (j >= tt) ? sTd[j - tt] : 0.0f;
        if (j == tt) v += dh;
        tmh[idx] = f2bf(v);
    }
    uint4* mp4 = (uint4*)(Mp + h * 2048);
    uint4* em4 = (uint4*)(Em + h * 2048);
    const uint4* smp4 = (const uint4*)sMp;
    const uint4* sem4 = (const uint4*)sEm;
    #pragma unroll
    for (int k = 0; k < 4; ++k) {
        mp4[k * 64 + tid] = smp4[k * 64 + tid];
        em4[k * 64 + tid] = sem4[k * 64 + tid];
    }
    const int gidx = h * 64 + tid;
    #pragma unroll
    for (int k = 0; k < 2; ++k) {
        int i = gidx + k * (NH * 64);
        float4 v = ((const float4*)W)[i];
        ushort4 o;
        o.x = f2bf(v.x); o.y = f2bf(v.y); o.z = f2bf(v.z); o.w = f2bf(v.w);
        ((ushort4*)Wbf)[i] = o;
    }
}

// ---------- MFMA chunked scan: one block per (b,h), 4 waves (unchanged) ----------
__global__ __launch_bounds__(256) void scan_mfma_kernel(
        const float* __restrict__ u,
        const float* __restrict__ w32c,
        const unsigned short* __restrict__ Mp,
        const unsigned short* __restrict__ Tm,
        const unsigned short* __restrict__ Em,
        unsigned short* __restrict__ ybf) {
    const int bh = blockIdx.x;
    const int h = bh & (NH - 1);
    const int tid = threadIdx.x;
    const int lane = tid & 63;
    const int wv = tid >> 6;
    const int g = lane >> 4, c = lane & 15;

    __shared__ __align__(16) char arena[26624];
    unsigned short* u_bf = (unsigned short*)arena;
    unsigned int*   ldsP = (unsigned int*)(arena + 8192);

    {
        const float4* up = (const float4*)(u + (size_t)bh * NL + tid * 16);
        float4 a = up[0], b4 = up[1], c4 = up[2], d4 = up[3];
        union { unsigned short us[16]; uint4 q[2]; } pk;
        pk.us[0]=f2bf(a.x); pk.us[1]=f2bf(a.y); pk.us[2]=f2bf(a.z); pk.us[3]=f2bf(a.w);
        pk.us[4]=f2bf(b4.x); pk.us[5]=f2bf(b4.y); pk.us[6]=f2bf(b4.z); pk.us[7]=f2bf(b4.w);
        pk.us[8]=f2bf(c4.x); pk.us[9]=f2bf(c4.y); pk.us[10]=f2bf(c4.z); pk.us[11]=f2bf(c4.w);
        pk.us[12]=f2bf(d4.x); pk.us[13]=f2bf(d4.y); pk.us[14]=f2bf(d4.z); pk.us[15]=f2bf(d4.w);
        uint4* dst = (uint4*)(u_bf + tid * 16);
        dst[0] = pk.q[0];
        dst[1] = pk.q[1];
    }
    __syncthreads();

    s8v bu[2];
    #pragma unroll
    for (int ntl = 0; ntl < 2; ++ntl)
        bu[ntl] = *(const s8v*)(u_bf + ((2 * wv + ntl) * 16 + c) * 32 + g * 8);

    const unsigned short* mph = Mp + h * 2048;
    f4v p1[4][2];
    #pragma unroll
    for (int mt = 0; mt < 4; ++mt) {
        s8v am = *(const s8v*)(mph + (mt * 16 + c) * 32 + g * 8);
        p1[mt][0] = (f4v){0.f,0.f,0.f,0.f};
        p1[mt][1] = (f4v){0.f,0.f,0.f,0.f};
        p1[mt][0] = __builtin_amdgcn_mfma_f32_16x16x32_bf16(am, bu[0], p1[mt][0], 0,0,0);
        p1[mt][1] = __builtin_amdgcn_mfma_f32_16x16x32_bf16(am, bu[1], p1[mt][1], 0,0,0);
    }
    #pragma unroll
    for (int mt = 0; mt < 4; ++mt)
        #pragma unroll
        for (int ntl = 0; ntl < 2; ++ntl) {
            const int chunk = (2 * wv + ntl) * 16 + c;
            f4v v = p1[mt][ntl];
            unsigned int lo = (unsigned int)f2bf(v[0]) | ((unsigned int)f2bf(v[1]) << 16);
            unsigned int hi = (unsigned int)f2bf(v[2]) | ((unsigned int)f2bf(v[3]) << 16);
            *(uint2*)&ldsP[chunk * 36 + mt * 8 + 2 * g] = make_uint2(lo, hi);
        }
    __syncthreads();

    if (tid < 64) {
        const int n = lane & 31, seg = lane >> 5;
        const float wr = w32c[h * 64 + 2 * n], wi = w32c[h * 64 + 2 * n + 1];
        float sr = 0.f, si = 0.f;
        const int base = seg * 64;
        for (int t = 0; t < 64; ++t) {
            const int chunk = base + t;
            unsigned int pv = ldsP[chunk * 36 + n];
            ldsP[chunk * 36 + n] =
                (unsigned int)f2bf(sr) | ((unsigned int)f2bf(si) << 16);
            float Pr = bf2f((unsigned short)(pv & 0xFFFF));
            float Pi = bf2f((unsigned short)(pv >> 16));
            float nsr = fmaf(wr, sr, fmaf(-wi, si, Pr));
            float nsi = fmaf(wr, si, fmaf(wi, sr, Pi));
            sr = nsr; si = nsi;
        }
        float tr = __shfl(sr, n, 64);
        float ti = __shfl(si, n, 64);
        if (seg == 1) {
            float gr = tr, gi = ti;
            for (int t = 0; t < 64; ++t) {
                const int chunk = 64 + t;
                unsigned int sv = ldsP[chunk * 36 + n];
                float fr2 = bf2f((unsigned short)(sv & 0xFFFF)) + gr;
                float fi2 = bf2f((unsigned short)(sv >> 16)) + gi;
                ldsP[chunk * 36 + n] =
                    (unsigned int)f2bf(fr2) | ((unsigned int)f2bf(fi2) << 16);
                float ngr = wr * gr - wi * gi;
                float ngi = fmaf(wr, gi, wi * gr);
                gr = ngr; gi = ngi;
            }
        }
    }
    __syncthreads();

    const unsigned short* tmh = Tm + h * 1024;
    const unsigned short* emh = Em + h * 2048;
    const unsigned short* sbase = (const unsigned short*)ldsP;
    f4v a2[2][2];
    #pragma unroll
    for (int mt = 0; mt < 2; ++mt) {
        a2[mt][0] = (f4v){0.f,0.f,0.f,0.f};
        a2[mt][1] = (f4v){0.f,0.f,0.f,0.f};
        s8v at = *(const s8v*)(tmh + (mt * 16 + c) * 32 + g * 8);
        a2[mt][0] = __builtin_amdgcn_mfma_f32_16x16x32_bf16(at, bu[0], a2[mt][0], 0,0,0);
        a2[mt][1] = __builtin_amdgcn_mfma_f32_16x16x32_bf16(at, bu[1], a2[mt][1], 0,0,0);
    }
    #pragma unroll
    for (int ksub = 0; ksub < 2; ++ksub) {
        s8v bs[2];
        #pragma unroll
        for (int ntl = 0; ntl < 2; ++ntl) {
            const int chunk = (2 * wv + ntl) * 16 + c;
            bs[ntl] = *(const s8v*)(sbase + chunk * 72 + ksub * 32 + g * 8);
        }
        #pragma unroll
        for (int mt = 0; mt < 2; ++mt) {
            s8v ae = *(const s8v*)(emh + (mt * 16 + c) * 64 + ksub * 32 + g * 8);
            a2[mt][0] = __builtin_amdgcn_mfma_f32_16x16x32_bf16(ae, bs[0], a2[mt][0], 0,0,0);
            a2[mt][1] = __builtin_amdgcn_mfma_f32_16x16x32_bf16(ae, bs[1], a2[mt][1], 0,0,0);
        }
    }

    unsigned short* yrow = ybf + (size_t)bh * NL;
    #pragma unroll
    for (int mt = 0; mt < 2; ++mt)
        #pragma unroll
        for (int ntl = 0; ntl < 2; ++ntl) {
            const int chunk = (2 * wv + ntl) * 16 + c;
            f4v v = a2[mt][ntl];
            unsigned short gs[4];
            #pragma unroll
            for (int r = 0; r < 4; ++r) {
                float x = v[r];
                gs[r] = f2bf(0.5f * x * (1.0f + erff(x * 0.70710678118654752f)));
            }
            unsigned int lo = (unsigned int)gs[0] | ((unsigned int)gs[1] << 16);
            unsigned int hi = (unsigned int)gs[2] | ((unsigned int)gs[3] << 16);
            *(uint2*)(yrow + chunk * 32 + mt * 16 + 4 * g) = make_uint2(lo, hi);
        }
}

// ---------------- MFMA GEMM + GLU: full-K LDS, one barrier, barrier-free K-loop ----------------
// Block = 512 threads (8 waves). Tile: ALL 256 o-pairs x 64 l, K = 256 fully staged.
// ldsY[l 0..63][kp 0..127 (+4 pad)] u32 = pair (y[2kp][l], y[2kp+1][l]); stride 132.
// Stage: thread owns one k-row half (64B contiguous, perfect coalescing), 4 uint4
// issued at once -> ONE latency exposure; 32 ds_write_b16 (4-way alias, ~1.6x).
// K-loop: 8 steps x {4 afr (W, L2-res), 4 bfr ds_read_b128, 16 MFMA}, NO barriers.
__global__ __launch_bounds__(512) void gemm_glu_mfma(
        const unsigned short* __restrict__ ybf,
        const unsigned short* __restrict__ Wbf,
        const float* __restrict__ bo,
        float* __restrict__ out) {
    const int l0 = blockIdx.x * 64;
    const int b  = blockIdx.y;
    const int tid = threadIdx.x;
    const int lane = tid & 63;
    const int wv = tid >> 6;            // 0..7
    const int g = lane >> 4, c = lane & 15;

    __shared__ __align__(16) unsigned int ldsY[64 * 132];  // 33792 B

    // ---- stage: full y[b, 0..256, l0..l0+64) transposed+packed ----
    {
        const int r  = tid >> 1;        // k row 0..255
        const int hh = tid & 1;         // l half: [hh*32, +32)
        const int kp = r >> 1, hb = r & 1;
        const unsigned short* ysrc = ybf + ((size_t)b * NH + r) * NL + l0 + hh * 32;
        uint4 v0 = ((const uint4*)ysrc)[0];
        uint4 v1 = ((const uint4*)ysrc)[1];
        uint4 v2 = ((const uint4*)ysrc)[2];
        uint4 v3 = ((const uint4*)ysrc)[3];
        unsigned short* lds16 = (unsigned short*)ldsY;
        const int base16 = ((hh * 32) * 132 + kp) * 2 + hb;
        u8h a0 = *(const u8h*)&v0, a1 = *(const u8h*)&v1;
        u8h a2 = *(const u8h*)&v2, a3 = *(const u8h*)&v3;
        #pragma unroll
        for (int j = 0; j < 8; ++j) {
            lds16[base16 + (j)      * 264] = a0[j];
            lds16[base16 + (j + 8)  * 264] = a1[j];
            lds16[base16 + (j + 16) * 264] = a2[j];
            lds16[base16 + (j + 24) * 264] = a3[j];
        }
    }
    __syncthreads();

    // ---- barrier-free K-loop ----
    f4v acc[4][4];
    #pragma unroll
    for (int m = 0; m < 4; ++m)
        #pragma unroll
        for (int n = 0; n < 4; ++n)
            acc[m][n] = (f4v){0.f, 0.f, 0.f, 0.f};

    int wrow[4];
    wrow[0] = wv * 32 + c;          // a-rows
    wrow[1] = wrow[0] + 16;
    wrow[2] = wrow[0] + 256;        // b-rows (GLU pair)
    wrow[3] = wrow[1] + 256;

    for (int ks = 0; ks < 8; ++ks) {
        s8v afr[4], bfr[4];
        #pragma unroll
        for (int m = 0; m < 4; ++m)
            afr[m] = *(const s8v*)(Wbf + wrow[m] * NH + ks * 32 + g * 8);
        #pragma unroll
        for (int n = 0; n < 4; ++n)
            bfr[n] = *(const s8v*)&ldsY[(n * 16 + c) * 132 + ks * 16 + g * 4];
        #pragma unroll
        for (int m = 0; m < 4; ++m)
            #pragma unroll
            for (int n = 0; n < 4; ++n)
                acc[m][n] = __builtin_amdgcn_mfma_f32_16x16x32_bf16(
                    afr[m], bfr[n], acc[m][n], 0, 0, 0);
    }

    // ---- epilogue: GLU over in-lane pairs acc[m] (a) / acc[m+2] (b) ----
    #pragma unroll
    for (int m = 0; m < 2; ++m) {
        const int o0 = wv * 32 + m * 16 + g * 4;
        float4 ba = *(const float4*)(bo + o0);
        float4 bb = *(const float4*)(bo + NH + o0);
        const float baj[4] = {ba.x, ba.y, ba.z, ba.w};
        const float bbj[4] = {bb.x, bb.y, bb.z, bb.w};
        #pragma unroll
        for (int j = 0; j < 4; ++j) {
            float* orow = out + ((size_t)(b * NH + o0 + j)) * NL + l0 + c;
            #pragma unroll
            for (int n = 0; n < 4; ++n) {
                float za = acc[m][n][j] + baj[j];
                float zb = acc[m + 2][n][j] + bbj[j];
                orow[n * 16] = za / (1.0f + expf(-zb));
            }
        }
    }
}

extern "C" void kernel_launch(void* const* d_in, const int* in_sizes, int n_in,
                              void* d_out, int out_size, void* d_ws, size_t ws_size,
                              hipStream_t stream) {
    (void)in_sizes; (void)n_in; (void)out_size; (void)ws_size;
    const float* u      = (const float*)d_in[0];
    const float* log_dt = (const float*)d_in[1];
    const float* Cr     = (const float*)d_in[2];
    const float* Ci     = (const float*)d_in[3];
    const float* lar    = (const float*)d_in[4];
    const float* aim    = (const float*)d_in[5];
    const float* Dvec   = (const float*)d_in[6];
    const float* W      = (const float*)d_in[7];
    const float* bo     = (const float*)d_in[8];
    float* out = (float*)d_out;

    char* ws = (char*)d_ws;
    float*          w32c = (float*)ws;                          // 64 KB
    unsigned short* Mp   = (unsigned short*)(ws + 65536);       // 1 MB
    unsigned short* Em   = (unsigned short*)(ws + 1114112);     // 1 MB
    unsigned short* Tm   = (unsigned short*)(ws + 2162688);     // 512 KB
    unsigned short* Wbf  = (unsigned short*)(ws + 2686976);     // 256 KB
    unsigned short* ybf  = (unsigned short*)(ws + 2949120);     // 32 MB

    precompute_kernel<<<dim3(NH), dim3(64), 0, stream>>>(
        log_dt, Cr, Ci, lar, aim, Dvec, w32c, Mp, Em, Tm, W, Wbf);
    scan_mfma_kernel<<<dim3(NB * NH), dim3(256), 0, stream>>>(u, w32c, Mp, Tm, Em, ybf);
    gemm_glu_mfma<<<dim3(NL / 64, NB), dim3(512), 0, stream>>>(ybf, Wbf, bo, out);
}

// Round 11
// 101.202 us; speedup vs baseline: 1.4109x; 1.0936x over previous
//
#include <hip/hip_runtime.h>

#define NB 16
#define NH 256
#define NL 4096
#define NN 32

typedef short s8v __attribute__((ext_vector_type(8)));
typedef float f4v __attribute__((ext_vector_type(4)));
typedef unsigned short u8h __attribute__((ext_vector_type(8)));

__device__ __forceinline__ unsigned short f2bf(float x) {
    unsigned int u = __float_as_uint(x);
    unsigned int r = u + 0x7FFFu + ((u >> 16) & 1u);
    return (unsigned short)(r >> 16);
}
__device__ __forceinline__ float bf2f(unsigned short b) {
    return __uint_as_float(((unsigned int)b) << 16);
}
// GELU via Abramowitz-Stegun 7.1.26 erf (|err| <= 1.5e-7, f32-noise level)
__device__ __forceinline__ float gelu_as(float x) {
    float ax = fabsf(x) * 0.70710678118654752f;
    float t = __builtin_amdgcn_rcpf(fmaf(0.3275911f, ax, 1.0f));
    float p = t * fmaf(t, fmaf(t, fmaf(t, fmaf(t, 1.061405429f, -1.453152027f),
                                       1.421413741f), -0.284496736f), 0.254829592f);
    float e = __expf(-ax * ax);
    float erfv = fmaf(-p, e, 1.0f);               // erf(|x|/sqrt2)
    erfv = __builtin_copysignf(erfv, x);
    return 0.5f * x * (1.0f + erfv);
}

// ---------- merged precompute: per h: w32 consts, Mp, Em, Tm (+ W->bf16 tail) ----------
__global__ __launch_bounds__(64) void precompute_kernel(
        const float* __restrict__ log_dt,
        const float* __restrict__ Cr,
        const float* __restrict__ Ci,
        const float* __restrict__ lar,
        const float* __restrict__ aim,
        const float* __restrict__ Dvec,
        float* __restrict__ w32c,
        unsigned short* __restrict__ Mp,
        unsigned short* __restrict__ Em,
        unsigned short* __restrict__ Tm,
        const float* __restrict__ W,
        unsigned short* __restrict__ Wbf) {
    const int h = blockIdx.x;
    const int tid = threadIdx.x;
    __shared__ float sRe[32][33];
    __shared__ float sTd[32];
    __shared__ unsigned short sMp[64 * 32];
    __shared__ unsigned short sEm[32 * 64];

    if (tid < 32) {
        const int n = tid;
        const int idx = h * 32 + n;
        float dt = expf(log_dt[h]);
        float ar = -expf(lar[idx]);
        float ai = aim[idx];
        float dar = ar * dt, dai = ai * dt;
        float er = expf(dar);
        float wr = er * cosf(dai), wi = er * sinf(dai);
        float Er = wr - 1.0f, Ei = wi;
        float den = ar * ar + ai * ai;
        float fr = (Er * ar + Ei * ai) / den;
        float fi = (Ei * ar - Er * ai) / den;
        float cr = Cr[idx], ci = Ci[idx];
        float c2r = 2.0f * (cr * fr - ci * fi);
        float c2i = 2.0f * (cr * fi + ci * fr);
        float e32 = expf(32.0f * dar);
        w32c[h * 64 + 2 * n]     = e32 * cosf(32.0f * dai);
        w32c[h * 64 + 2 * n + 1] = e32 * sinf(32.0f * dai);
        float pr = 1.0f, pi = 0.0f;
        for (int e = 0; e < 32; ++e) {
            sMp[(2 * n) * 32 + (31 - e)]     = f2bf(pr);
            sMp[(2 * n + 1) * 32 + (31 - e)] = f2bf(pi);
            float npr = pr * wr - pi * wi;
            pi = fmaf(pr, wi, pi * wr);
            pr = npr;
        }
        float gr = c2r, gi = c2i;
        for (int e = 0; e <= 32; ++e) {
            if (e < 32) sRe[e][n] = gr;
            if (e >= 1) {
                sEm[(e - 1) * 64 + 2 * n]     = f2bf(gr);
                sEm[(e - 1) * 64 + 2 * n + 1] = f2bf(-gi);
            }
            float ngr = gr * wr - gi * wi;
            gi = fmaf(gr, wi, gi * wr);
            gr = ngr;
        }
    }
    __syncthreads();
    if (tid < 32) {
        float a = 0.0f;
        #pragma unroll
        for (int n = 0; n < 32; ++n) a += sRe[tid][n];
        sTd[tid] = a;
    }
    __syncthreads();
    const float dh = Dvec[h];
    unsigned short* tmh = Tm + h * 1024;
    for (int i = 0; i < 16; ++i) {
        int idx = tid * 16 + i;
        int j = idx >> 5, tt = idx & 31;
        float v = (j >= tt) ? sTd[j - tt] : 0.0f;
        if (j == tt) v += dh;
        tmh[idx] = f2bf(v);
    }
    uint4* mp4 = (uint4*)(Mp + h * 2048);
    uint4* em4 = (uint4*)(Em + h * 2048);
    const uint4* smp4 = (const uint4*)sMp;
    const uint4* sem4 = (const uint4*)sEm;
    #pragma unroll
    for (int k = 0; k < 4; ++k) {
        mp4[k * 64 + tid] = smp4[k * 64 + tid];
        em4[k * 64 + tid] = sem4[k * 64 + tid];
    }
    const int gidx = h * 64 + tid;
    #pragma unroll
    for (int k = 0; k < 2; ++k) {
        int i = gidx + k * (NH * 64);
        float4 v = ((const float4*)W)[i];
        ushort4 o;
        o.x = f2bf(v.x); o.y = f2bf(v.y); o.z = f2bf(v.z); o.w = f2bf(v.w);
        ((ushort4*)Wbf)[i] = o;
    }
}

// ---------- MFMA chunked scan: one block per (b,h), 4 waves ----------
__global__ __launch_bounds__(256) void scan_mfma_kernel(
        const float* __restrict__ u,
        const float* __restrict__ w32c,
        const unsigned short* __restrict__ Mp,
        const unsigned short* __restrict__ Tm,
        const unsigned short* __restrict__ Em,
        unsigned short* __restrict__ ybf) {
    const int bh = blockIdx.x;
    const int h = bh & (NH - 1);
    const int tid = threadIdx.x;
    const int lane = tid & 63;
    const int wv = tid >> 6;
    const int g = lane >> 4, c = lane & 15;

    __shared__ __align__(16) char arena[26624];
    unsigned short* u_bf = (unsigned short*)arena;
    unsigned int*   ldsP = (unsigned int*)(arena + 8192);

    {
        const float4* up = (const float4*)(u + (size_t)bh * NL + tid * 16);
        float4 a = up[0], b4 = up[1], c4 = up[2], d4 = up[3];
        union { unsigned short us[16]; uint4 q[2]; } pk;
        pk.us[0]=f2bf(a.x); pk.us[1]=f2bf(a.y); pk.us[2]=f2bf(a.z); pk.us[3]=f2bf(a.w);
        pk.us[4]=f2bf(b4.x); pk.us[5]=f2bf(b4.y); pk.us[6]=f2bf(b4.z); pk.us[7]=f2bf(b4.w);
        pk.us[8]=f2bf(c4.x); pk.us[9]=f2bf(c4.y); pk.us[10]=f2bf(c4.z); pk.us[11]=f2bf(c4.w);
        pk.us[12]=f2bf(d4.x); pk.us[13]=f2bf(d4.y); pk.us[14]=f2bf(d4.z); pk.us[15]=f2bf(d4.w);
        uint4* dst = (uint4*)(u_bf + tid * 16);
        dst[0] = pk.q[0];
        dst[1] = pk.q[1];
    }
    __syncthreads();

    s8v bu[2];
    #pragma unroll
    for (int ntl = 0; ntl < 2; ++ntl)
        bu[ntl] = *(const s8v*)(u_bf + ((2 * wv + ntl) * 16 + c) * 32 + g * 8);

    const unsigned short* mph = Mp + h * 2048;
    f4v p1[4][2];
    #pragma unroll
    for (int mt = 0; mt < 4; ++mt) {
        s8v am = *(const s8v*)(mph + (mt * 16 + c) * 32 + g * 8);
        p1[mt][0] = (f4v){0.f,0.f,0.f,0.f};
        p1[mt][1] = (f4v){0.f,0.f,0.f,0.f};
        p1[mt][0] = __builtin_amdgcn_mfma_f32_16x16x32_bf16(am, bu[0], p1[mt][0], 0,0,0);
        p1[mt][1] = __builtin_amdgcn_mfma_f32_16x16x32_bf16(am, bu[1], p1[mt][1], 0,0,0);
    }
    #pragma unroll
    for (int mt = 0; mt < 4; ++mt)
        #pragma unroll
        for (int ntl = 0; ntl < 2; ++ntl) {
            const int chunk = (2 * wv + ntl) * 16 + c;
            f4v v = p1[mt][ntl];
            unsigned int lo = (unsigned int)f2bf(v[0]) | ((unsigned int)f2bf(v[1]) << 16);
            unsigned int hi = (unsigned int)f2bf(v[2]) | ((unsigned int)f2bf(v[3]) << 16);
            *(uint2*)&ldsP[chunk * 36 + mt * 8 + 2 * g] = make_uint2(lo, hi);
        }
    __syncthreads();

    if (tid < 64) {
        const int n = lane & 31, seg = lane >> 5;
        const float wr = w32c[h * 64 + 2 * n], wi = w32c[h * 64 + 2 * n + 1];
        float sr = 0.f, si = 0.f;
        const int base = seg * 64;
        for (int t = 0; t < 64; ++t) {
            const int chunk = base + t;
            unsigned int pv = ldsP[chunk * 36 + n];
            ldsP[chunk * 36 + n] =
                (unsigned int)f2bf(sr) | ((unsigned int)f2bf(si) << 16);
            float Pr = bf2f((unsigned short)(pv & 0xFFFF));
            float Pi = bf2f((unsigned short)(pv >> 16));
            float nsr = fmaf(wr, sr, fmaf(-wi, si, Pr));
            float nsi = fmaf(wr, si, fmaf(wi, sr, Pi));
            sr = nsr; si = nsi;
        }
        float tr = __shfl(sr, n, 64);
        float ti = __shfl(si, n, 64);
        if (seg == 1) {
            float gr = tr, gi = ti;
            for (int t = 0; t < 64; ++t) {
                const int chunk = 64 + t;
                unsigned int sv = ldsP[chunk * 36 + n];
                float fr2 = bf2f((unsigned short)(sv & 0xFFFF)) + gr;
                float fi2 = bf2f((unsigned short)(sv >> 16)) + gi;
                ldsP[chunk * 36 + n] =
                    (unsigned int)f2bf(fr2) | ((unsigned int)f2bf(fi2) << 16);
                float ngr = wr * gr - wi * gi;
                float ngi = fmaf(wr, gi, wi * gr);
                gr = ngr; gi = ngi;
            }
        }
    }
    __syncthreads();

    const unsigned short* tmh = Tm + h * 1024;
    const unsigned short* emh = Em + h * 2048;
    const unsigned short* sbase = (const unsigned short*)ldsP;
    f4v a2[2][2];
    #pragma unroll
    for (int mt = 0; mt < 2; ++mt) {
        a2[mt][0] = (f4v){0.f,0.f,0.f,0.f};
        a2[mt][1] = (f4v){0.f,0.f,0.f,0.f};
        s8v at = *(const s8v*)(tmh + (mt * 16 + c) * 32 + g * 8);
        a2[mt][0] = __builtin_amdgcn_mfma_f32_16x16x32_bf16(at, bu[0], a2[mt][0], 0,0,0);
        a2[mt][1] = __builtin_amdgcn_mfma_f32_16x16x32_bf16(at, bu[1], a2[mt][1], 0,0,0);
    }
    #pragma unroll
    for (int ksub = 0; ksub < 2; ++ksub) {
        s8v bs[2];
        #pragma unroll
        for (int ntl = 0; ntl < 2; ++ntl) {
            const int chunk = (2 * wv + ntl) * 16 + c;
            bs[ntl] = *(const s8v*)(sbase + chunk * 72 + ksub * 32 + g * 8);
        }
        #pragma unroll
        for (int mt = 0; mt < 2; ++mt) {
            s8v ae = *(const s8v*)(emh + (mt * 16 + c) * 64 + ksub * 32 + g * 8);
            a2[mt][0] = __builtin_amdgcn_mfma_f32_16x16x32_bf16(ae, bs[0], a2[mt][0], 0,0,0);
            a2[mt][1] = __builtin_amdgcn_mfma_f32_16x16x32_bf16(ae, bs[1], a2[mt][1], 0,0,0);
        }
    }

    unsigned short* yrow = ybf + (size_t)bh * NL;
    #pragma unroll
    for (int mt = 0; mt < 2; ++mt)
        #pragma unroll
        for (int ntl = 0; ntl < 2; ++ntl) {
            const int chunk = (2 * wv + ntl) * 16 + c;
            f4v v = a2[mt][ntl];
            unsigned short gs[4];
            #pragma unroll
            for (int r = 0; r < 4; ++r)
                gs[r] = f2bf(gelu_as(v[r]));
            unsigned int lo = (unsigned int)gs[0] | ((unsigned int)gs[1] << 16);
            unsigned int hi = (unsigned int)gs[2] | ((unsigned int)gs[3] << 16);
            *(uint2*)(yrow + chunk * 32 + mt * 16 + 4 * g) = make_uint2(lo, hi);
        }
}

// ---------------- MFMA GEMM + GLU: full-K LDS, unrolled K-loop + W prefetch ----------------
__global__ __launch_bounds__(512) void gemm_glu_mfma(
        const unsigned short* __restrict__ ybf,
        const unsigned short* __restrict__ Wbf,
        const float* __restrict__ bo,
        float* __restrict__ out) {
    const int l0 = blockIdx.x * 64;
    const int b  = blockIdx.y;
    const int tid = threadIdx.x;
    const int lane = tid & 63;
    const int wv = tid >> 6;            // 0..7
    const int g = lane >> 4, c = lane & 15;

    __shared__ __align__(16) unsigned int ldsY[64 * 132];  // 33792 B

    // ---- stage: full y[b, 0..256, l0..l0+64) transposed+packed ----
    {
        const int r  = tid >> 1;        // k row 0..255
        const int hh = tid & 1;         // l half
        const int kp = r >> 1, hb = r & 1;
        const unsigned short* ysrc = ybf + ((size_t)b * NH + r) * NL + l0 + hh * 32;
        uint4 v0 = ((const uint4*)ysrc)[0];
        uint4 v1 = ((const uint4*)ysrc)[1];
        uint4 v2 = ((const uint4*)ysrc)[2];
        uint4 v3 = ((const uint4*)ysrc)[3];
        unsigned short* lds16 = (unsigned short*)ldsY;
        const int base16 = ((hh * 32) * 132 + kp) * 2 + hb;
        u8h a0 = *(const u8h*)&v0, a1 = *(const u8h*)&v1;
        u8h a2 = *(const u8h*)&v2, a3 = *(const u8h*)&v3;
        #pragma unroll
        for (int j = 0; j < 8; ++j) {
            lds16[base16 + (j)      * 264] = a0[j];
            lds16[base16 + (j + 8)  * 264] = a1[j];
            lds16[base16 + (j + 16) * 264] = a2[j];
            lds16[base16 + (j + 24) * 264] = a3[j];
        }
    }
    __syncthreads();

    f4v acc[4][4];
    #pragma unroll
    for (int m = 0; m < 4; ++m)
        #pragma unroll
        for (int n = 0; n < 4; ++n)
            acc[m][n] = (f4v){0.f, 0.f, 0.f, 0.f};

    int wrow[4];
    wrow[0] = wv * 32 + c;          // a-rows
    wrow[1] = wrow[0] + 16;
    wrow[2] = wrow[0] + 256;        // b-rows (GLU pair)
    wrow[3] = wrow[1] + 256;

    // depth-1 W prefetch, fully unrolled K-loop
    s8v afr[4];
    #pragma unroll
    for (int m = 0; m < 4; ++m)
        afr[m] = *(const s8v*)(Wbf + wrow[m] * NH + g * 8);

    #pragma unroll
    for (int ks = 0; ks < 8; ++ks) {
        s8v acur[4];
        #pragma unroll
        for (int m = 0; m < 4; ++m) acur[m] = afr[m];
        if (ks < 7) {
            #pragma unroll
            for (int m = 0; m < 4; ++m)
                afr[m] = *(const s8v*)(Wbf + wrow[m] * NH + (ks + 1) * 32 + g * 8);
        }
        s8v bfr[4];
        #pragma unroll
        for (int n = 0; n < 4; ++n)
            bfr[n] = *(const s8v*)&ldsY[(n * 16 + c) * 132 + ks * 16 + g * 4];
        #pragma unroll
        for (int m = 0; m < 4; ++m)
            #pragma unroll
            for (int n = 0; n < 4; ++n)
                acc[m][n] = __builtin_amdgcn_mfma_f32_16x16x32_bf16(
                    acur[m], bfr[n], acc[m][n], 0, 0, 0);
    }

    // ---- epilogue: GLU over in-lane pairs acc[m] (a) / acc[m+2] (b) ----
    #pragma unroll
    for (int m = 0; m < 2; ++m) {
        const int o0 = wv * 32 + m * 16 + g * 4;
        float4 ba = *(const float4*)(bo + o0);
        float4 bb = *(const float4*)(bo + NH + o0);
        const float baj[4] = {ba.x, ba.y, ba.z, ba.w};
        const float bbj[4] = {bb.x, bb.y, bb.z, bb.w};
        #pragma unroll
        for (int j = 0; j < 4; ++j) {
            float* orow = out + ((size_t)(b * NH + o0 + j)) * NL + l0 + c;
            #pragma unroll
            for (int n = 0; n < 4; ++n) {
                float za = acc[m][n][j] + baj[j];
                float zb = acc[m + 2][n][j] + bbj[j];
                orow[n * 16] = za / (1.0f + expf(-zb));
            }
        }
    }
}

extern "C" void kernel_launch(void* const* d_in, const int* in_sizes, int n_in,
                              void* d_out, int out_size, void* d_ws, size_t ws_size,
                              hipStream_t stream) {
    (void)in_sizes; (void)n_in; (void)out_size; (void)ws_size;
    const float* u      = (const float*)d_in[0];
    const float* log_dt = (const float*)d_in[1];
    const float* Cr     = (const float*)d_in[2];
    const float* Ci     = (const float*)d_in[3];
    const float* lar    = (const float*)d_in[4];
    const float* aim    = (const float*)d_in[5];
    const float* Dvec   = (const float*)d_in[6];
    const float* W      = (const float*)d_in[7];
    const float* bo     = (const float*)d_in[8];
    float* out = (float*)d_out;

    char* ws = (char*)d_ws;
    float*          w32c = (float*)ws;                          // 64 KB
    unsigned short* Mp   = (unsigned short*)(ws + 65536);       // 1 MB
    unsigned short* Em   = (unsigned short*)(ws + 1114112);     // 1 MB
    unsigned short* Tm   = (unsigned short*)(ws + 2162688);     // 512 KB
    unsigned short* Wbf  = (unsigned short*)(ws + 2686976);     // 256 KB
    unsigned short* ybf  = (unsigned short*)(ws + 2949120);     // 32 MB

    precompute_kernel<<<dim3(NH), dim3(64), 0, stream>>>(
        log_dt, Cr, Ci, lar, aim, Dvec, w32c, Mp, Em, Tm, W, Wbf);
    scan_mfma_kernel<<<dim3(NB * NH), dim3(256), 0, stream>>>(u, w32c, Mp, Tm, Em, ybf);
    gemm_glu_mfma<<<dim3(NL / 64, NB), dim3(512), 0, stream>>>(ybf, Wbf, bo, out);
}

// Round 13
// 99.731 us; speedup vs baseline: 1.4317x; 1.0148x over previous
//
#include <hip/hip_runtime.h>

#define NB 16
#define NH 256
#define NL 4096
#define NN 32

typedef short s8v __attribute__((ext_vector_type(8)));
typedef float f4v __attribute__((ext_vector_type(4)));
typedef unsigned short u8h __attribute__((ext_vector_type(8)));

__device__ __forceinline__ unsigned short f2bf(float x) {
    unsigned int u = __float_as_uint(x);
    unsigned int r = u + 0x7FFFu + ((u >> 16) & 1u);
    return (unsigned short)(r >> 16);
}
__device__ __forceinline__ float bf2f(unsigned short b) {
    return __uint_as_float(((unsigned int)b) << 16);
}

// ---------- merged precompute (unchanged) ----------
__global__ __launch_bounds__(64) void precompute_kernel(
        const float* __restrict__ log_dt,
        const float* __restrict__ Cr,
        const float* __restrict__ Ci,
        const float* __restrict__ lar,
        const float* __restrict__ aim,
        const float* __restrict__ Dvec,
        float* __restrict__ w32c,
        unsigned short* __restrict__ Mp,
        unsigned short* __restrict__ Em,
        unsigned short* __restrict__ Tm,
        const float* __restrict__ W,
        unsigned short* __restrict__ Wbf) {
    const int h = blockIdx.x;
    const int tid = threadIdx.x;
    __shared__ float sRe[32][33];
    __shared__ float sTd[32];
    __shared__ unsigned short sMp[64 * 32];
    __shared__ unsigned short sEm[32 * 64];

    if (tid < 32) {
        const int n = tid;
        const int idx = h * 32 + n;
        float dt = expf(log_dt[h]);
        float ar = -expf(lar[idx]);
        float ai = aim[idx];
        float dar = ar * dt, dai = ai * dt;
        float er = expf(dar);
        float wr = er * cosf(dai), wi = er * sinf(dai);
        float Er = wr - 1.0f, Ei = wi;
        float den = ar * ar + ai * ai;
        float fr = (Er * ar + Ei * ai) / den;
        float fi = (Ei * ar - Er * ai) / den;
        float cr = Cr[idx], ci = Ci[idx];
        float c2r = 2.0f * (cr * fr - ci * fi);
        float c2i = 2.0f * (cr * fi + ci * fr);
        float e32 = expf(32.0f * dar);
        w32c[h * 64 + 2 * n]     = e32 * cosf(32.0f * dai);
        w32c[h * 64 + 2 * n + 1] = e32 * sinf(32.0f * dai);
        float pr = 1.0f, pi = 0.0f;
        for (int e = 0; e < 32; ++e) {
            sMp[(2 * n) * 32 + (31 - e)]     = f2bf(pr);
            sMp[(2 * n + 1) * 32 + (31 - e)] = f2bf(pi);
            float npr = pr * wr - pi * wi;
            pi = fmaf(pr, wi, pi * wr);
            pr = npr;
        }
        float gr = c2r, gi = c2i;
        for (int e = 0; e <= 32; ++e) {
            if (e < 32) sRe[e][n] = gr;
            if (e >= 1) {
                sEm[(e - 1) * 64 + 2 * n]     = f2bf(gr);
                sEm[(e - 1) * 64 + 2 * n + 1] = f2bf(-gi);
            }
            float ngr = gr * wr - gi * wi;
            gi = fmaf(gr, wi, gi * wr);
            gr = ngr;
        }
    }
    __syncthreads();
    if (tid < 32) {
        float a = 0.0f;
        #pragma unroll
        for (int n = 0; n < 32; ++n) a += sRe[tid][n];
        sTd[tid] = a;
    }
    __syncthreads();
    const float dh = Dvec[h];
    unsigned short* tmh = Tm + h * 1024;
    for (int i = 0; i < 16; ++i) {
        int idx = tid * 16 + i;
        int j = idx >> 5, tt = idx & 31;
        float v = (j >= tt) ? sTd[j - tt] : 0.0f;
        if (j == tt) v += dh;
        tmh[idx] = f2bf(v);
    }
    uint4* mp4 = (uint4*)(Mp + h * 2048);
    uint4* em4 = (uint4*)(Em + h * 2048);
    const uint4* smp4 = (const uint4*)sMp;
    const uint4* sem4 = (const uint4*)sEm;
    #pragma unroll
    for (int k = 0; k < 4; ++k) {
        mp4[k * 64 + tid] = smp4[k * 64 + tid];
        em4[k * 64 + tid] = sem4[k * 64 + tid];
    }
    const int gidx = h * 64 + tid;
    #pragma unroll
    for (int k = 0; k < 2; ++k) {
        int i = gidx + k * (NH * 64);
        float4 v = ((const float4*)W)[i];
        ushort4 o;
        o.x = f2bf(v.x); o.y = f2bf(v.y); o.z = f2bf(v.z); o.w = f2bf(v.w);
        ((ushort4*)Wbf)[i] = o;
    }
}

// ---------- MFMA chunked scan: 4-segment 2-wave phase B, EXACT erf GELU ----------
__global__ __launch_bounds__(256) void scan_mfma_kernel(
        const float* __restrict__ u,
        const float* __restrict__ w32c,
        const unsigned short* __restrict__ Mp,
        const unsigned short* __restrict__ Tm,
        const unsigned short* __restrict__ Em,
        unsigned short* __restrict__ ybf) {
    const int bh = blockIdx.x;
    const int h = bh & (NH - 1);
    const int tid = threadIdx.x;
    const int lane = tid & 63;
    const int wv = tid >> 6;
    const int g = lane >> 4, c = lane & 15;

    __shared__ __align__(16) char arena[26624];
    unsigned short* u_bf = (unsigned short*)arena;            // [4096] bf16 (dead after bu load)
    float*          ldsT = (float*)arena;                     // [4 seg][32 n][2] f32, overlaps u_bf
    unsigned int*   ldsP = (unsigned int*)(arena + 8192);     // [128][36] u32

    {
        const float4* up = (const float4*)(u + (size_t)bh * NL + tid * 16);
        float4 a = up[0], b4 = up[1], c4 = up[2], d4 = up[3];
        union { unsigned short us[16]; uint4 q[2]; } pk;
        pk.us[0]=f2bf(a.x); pk.us[1]=f2bf(a.y); pk.us[2]=f2bf(a.z); pk.us[3]=f2bf(a.w);
        pk.us[4]=f2bf(b4.x); pk.us[5]=f2bf(b4.y); pk.us[6]=f2bf(b4.z); pk.us[7]=f2bf(b4.w);
        pk.us[8]=f2bf(c4.x); pk.us[9]=f2bf(c4.y); pk.us[10]=f2bf(c4.z); pk.us[11]=f2bf(c4.w);
        pk.us[12]=f2bf(d4.x); pk.us[13]=f2bf(d4.y); pk.us[14]=f2bf(d4.z); pk.us[15]=f2bf(d4.w);
        uint4* dst = (uint4*)(u_bf + tid * 16);
        dst[0] = pk.q[0];
        dst[1] = pk.q[1];
    }
    __syncthreads();

    s8v bu[2];
    #pragma unroll
    for (int ntl = 0; ntl < 2; ++ntl)
        bu[ntl] = *(const s8v*)(u_bf + ((2 * wv + ntl) * 16 + c) * 32 + g * 8);

    const unsigned short* mph = Mp + h * 2048;
    f4v p1[4][2];
    #pragma unroll
    for (int mt = 0; mt < 4; ++mt) {
        s8v am = *(const s8v*)(mph + (mt * 16 + c) * 32 + g * 8);
        p1[mt][0] = (f4v){0.f,0.f,0.f,0.f};
        p1[mt][1] = (f4v){0.f,0.f,0.f,0.f};
        p1[mt][0] = __builtin_amdgcn_mfma_f32_16x16x32_bf16(am, bu[0], p1[mt][0], 0,0,0);
        p1[mt][1] = __builtin_amdgcn_mfma_f32_16x16x32_bf16(am, bu[1], p1[mt][1], 0,0,0);
    }
    #pragma unroll
    for (int mt = 0; mt < 4; ++mt)
        #pragma unroll
        for (int ntl = 0; ntl < 2; ++ntl) {
            const int chunk = (2 * wv + ntl) * 16 + c;
            f4v v = p1[mt][ntl];
            unsigned int lo = (unsigned int)f2bf(v[0]) | ((unsigned int)f2bf(v[1]) << 16);
            unsigned int hi = (unsigned int)f2bf(v[2]) | ((unsigned int)f2bf(v[3]) << 16);
            *(uint2*)&ldsP[chunk * 36 + mt * 8 + 2 * g] = make_uint2(lo, hi);
        }
    __syncthreads();  // P complete; u_bf region now reusable as ldsT

    // ---- phase B1: 4 segments x 32 chunks on 2 waves; local exclusive scans ----
    float wr_b = 0.f, wi_b = 0.f;
    if (tid < 128) {
        const int n = tid & 31, seg = tid >> 5;
        wr_b = w32c[h * 64 + 2 * n];
        wi_b = w32c[h * 64 + 2 * n + 1];
        float sr = 0.f, si = 0.f;
        const int base = seg * 32;
        for (int t = 0; t < 32; ++t) {
            const int chunk = base + t;
            unsigned int pv = ldsP[chunk * 36 + n];
            ldsP[chunk * 36 + n] =
                (unsigned int)f2bf(sr) | ((unsigned int)f2bf(si) << 16);  // exclusive local
            float Pr = bf2f((unsigned short)(pv & 0xFFFF));
            float Pi = bf2f((unsigned short)(pv >> 16));
            float nsr = fmaf(wr_b, sr, fmaf(-wi_b, si, Pr));
            float nsi = fmaf(wr_b, si, fmaf(wi_b, sr, Pi));
            sr = nsr; si = nsi;
        }
        *(float2*)&ldsT[(seg * 32 + n) * 2] = make_float2(sr, si);  // T_seg
    }
    __syncthreads();
    // ---- phase B2: fixup with cross-segment prefix Q ----
    if (tid < 128) {
        const int n = tid & 31, seg = tid >> 5;
        if (seg > 0) {
            // w^1024 = w32^32 via 5 squarings
            float qr = wr_b, qi = wi_b;
            #pragma unroll
            for (int sq = 0; sq < 5; ++sq) {
                float nr = qr * qr - qi * qi;
                float ni = 2.0f * qr * qi;
                qr = nr; qi = ni;
            }
            float Qr = 0.f, Qi = 0.f;
            #pragma unroll
            for (int sp = 0; sp < 3; ++sp) {
                float2 Tv = *(const float2*)&ldsT[(sp * 32 + n) * 2];
                if (sp < seg) {
                    float nQr = fmaf(qr, Qr, fmaf(-qi, Qi, Tv.x));
                    float nQi = fmaf(qr, Qi, fmaf(qi, Qr, Tv.y));
                    Qr = nQr; Qi = nQi;
                }
            }
            float gr = Qr, gi = Qi;
            const int base = seg * 32;
            for (int t = 0; t < 32; ++t) {
                const int chunk = base + t;
                unsigned int sv = ldsP[chunk * 36 + n];
                float fr2 = bf2f((unsigned short)(sv & 0xFFFF)) + gr;
                float fi2 = bf2f((unsigned short)(sv >> 16)) + gi;
                ldsP[chunk * 36 + n] =
                    (unsigned int)f2bf(fr2) | ((unsigned int)f2bf(fi2) << 16);
                float ngr = wr_b * gr - wi_b * gi;
                float ngi = fmaf(wr_b, gi, wi_b * gr);
                gr = ngr; gi = ngi;
            }
        }
    }
    __syncthreads();

    const unsigned short* tmh = Tm + h * 1024;
    const unsigned short* emh = Em + h * 2048;
    const unsigned short* sbase = (const unsigned short*)ldsP;
    f4v a2[2][2];
    #pragma unroll
    for (int mt = 0; mt < 2; ++mt) {
        a2[mt][0] = (f4v){0.f,0.f,0.f,0.f};
        a2[mt][1] = (f4v){0.f,0.f,0.f,0.f};
        s8v at = *(const s8v*)(tmh + (mt * 16 + c) * 32 + g * 8);
        a2[mt][0] = __builtin_amdgcn_mfma_f32_16x16x32_bf16(at, bu[0], a2[mt][0], 0,0,0);
        a2[mt][1] = __builtin_amdgcn_mfma_f32_16x16x32_bf16(at, bu[1], a2[mt][1], 0,0,0);
    }
    #pragma unroll
    for (int ksub = 0; ksub < 2; ++ksub) {
        s8v bs[2];
        #pragma unroll
        for (int ntl = 0; ntl < 2; ++ntl) {
            const int chunk = (2 * wv + ntl) * 16 + c;
            bs[ntl] = *(const s8v*)(sbase + chunk * 72 + ksub * 32 + g * 8);
        }
        #pragma unroll
        for (int mt = 0; mt < 2; ++mt) {
            s8v ae = *(const s8v*)(emh + (mt * 16 + c) * 64 + ksub * 32 + g * 8);
            a2[mt][0] = __builtin_amdgcn_mfma_f32_16x16x32_bf16(ae, bs[0], a2[mt][0], 0,0,0);
            a2[mt][1] = __builtin_amdgcn_mfma_f32_16x16x32_bf16(ae, bs[1], a2[mt][1], 0,0,0);
        }
    }

    unsigned short* yrow = ybf + (size_t)bh * NL;
    #pragma unroll
    for (int mt = 0; mt < 2; ++mt)
        #pragma unroll
        for (int ntl = 0; ntl < 2; ++ntl) {
            const int chunk = (2 * wv + ntl) * 16 + c;
            f4v v = a2[mt][ntl];
            unsigned short gs[4];
            #pragma unroll
            for (int r = 0; r < 4; ++r) {
                float x = v[r];
                gs[r] = f2bf(0.5f * x * (1.0f + erff(x * 0.70710678118654752f)));
            }
            unsigned int lo = (unsigned int)gs[0] | ((unsigned int)gs[1] << 16);
            unsigned int hi = (unsigned int)gs[2] | ((unsigned int)gs[3] << 16);
            *(uint2*)(yrow + chunk * 32 + mt * 16 + 4 * g) = make_uint2(lo, hi);
        }
}

// ---------------- MFMA GEMM + GLU: full-K LDS, XOR-swizzled staging ----------------
__global__ __launch_bounds__(512) void gemm_glu_mfma(
        const unsigned short* __restrict__ ybf,
        const unsigned short* __restrict__ Wbf,
        const float* __restrict__ bo,
        float* __restrict__ out) {
    const int l0 = blockIdx.x * 64;
    const int b  = blockIdx.y;
    const int tid = threadIdx.x;
    const int lane = tid & 63;
    const int wv = tid >> 6;            // 0..7
    const int g = lane >> 4, c = lane & 15;

    __shared__ __align__(16) unsigned int ldsY[64 * 132];  // 33792 B

    // ---- stage: y[b, 0..256, l0..l0+64) transposed+packed, swizzled ----
    {
        const int r  = tid >> 1;        // k row 0..255
        const int hh = tid & 1;         // l half
        const int kp = r >> 1, hb = r & 1;
        const int kps = kp ^ (hh << 4); // XOR swizzle
        const unsigned short* ysrc = ybf + ((size_t)b * NH + r) * NL + l0 + hh * 32;
        uint4 v0 = ((const uint4*)ysrc)[0];
        uint4 v1 = ((const uint4*)ysrc)[1];
        uint4 v2 = ((const uint4*)ysrc)[2];
        uint4 v3 = ((const uint4*)ysrc)[3];
        unsigned short* lds16 = (unsigned short*)ldsY;
        const int base16 = ((hh * 32) * 132 + kps) * 2 + hb;
        u8h a0 = *(const u8h*)&v0, a1 = *(const u8h*)&v1;
        u8h a2 = *(const u8h*)&v2, a3 = *(const u8h*)&v3;
        #pragma unroll
        for (int j = 0; j < 8; ++j) {
            lds16[base16 + (j)      * 264] = a0[j];
            lds16[base16 + (j + 8)  * 264] = a1[j];
            lds16[base16 + (j + 16) * 264] = a2[j];
            lds16[base16 + (j + 24) * 264] = a3[j];
        }
    }
    __syncthreads();

    f4v acc[4][4];
    #pragma unroll
    for (int m = 0; m < 4; ++m)
        #pragma unroll
        for (int n = 0; n < 4; ++n)
            acc[m][n] = (f4v){0.f, 0.f, 0.f, 0.f};

    int wrow[4];
    wrow[0] = wv * 32 + c;          // a-rows
    wrow[1] = wrow[0] + 16;
    wrow[2] = wrow[0] + 256;        // b-rows (GLU pair)
    wrow[3] = wrow[1] + 256;

    // depth-1 W prefetch, fully unrolled K-loop
    s8v afr[4];
    #pragma unroll
    for (int m = 0; m < 4; ++m)
        afr[m] = *(const s8v*)(Wbf + wrow[m] * NH + g * 8);

    #pragma unroll
    for (int ks = 0; ks < 8; ++ks) {
        s8v acur[4];
        #pragma unroll
        for (int m = 0; m < 4; ++m) acur[m] = afr[m];
        if (ks < 7) {
            #pragma unroll
            for (int m = 0; m < 4; ++m)
                afr[m] = *(const s8v*)(Wbf + wrow[m] * NH + (ks + 1) * 32 + g * 8);
        }
        s8v bfr[4];
        #pragma unroll
        for (int n = 0; n < 4; ++n) {
            const int colb = (ks * 16 + g * 4) ^ ((n >> 1) << 4);  // un-swizzle
            bfr[n] = *(const s8v*)&ldsY[(n * 16 + c) * 132 + colb];
        }
        #pragma unroll
        for (int m = 0; m < 4; ++m)
            #pragma unroll
            for (int n = 0; n < 4; ++n)
                acc[m][n] = __builtin_amdgcn_mfma_f32_16x16x32_bf16(
                    acur[m], bfr[n], acc[m][n], 0, 0, 0);
    }

    // ---- epilogue: GLU over in-lane pairs acc[m] (a) / acc[m+2] (b) ----
    #pragma unroll
    for (int m = 0; m < 2; ++m) {
        const int o0 = wv * 32 + m * 16 + g * 4;
        float4 ba = *(const float4*)(bo + o0);
        float4 bb = *(const float4*)(bo + NH + o0);
        const float baj[4] = {ba.x, ba.y, ba.z, ba.w};
        const float bbj[4] = {bb.x, bb.y, bb.z, bb.w};
        #pragma unroll
        for (int j = 0; j < 4; ++j) {
            float* orow = out + ((size_t)(b * NH + o0 + j)) * NL + l0 + c;
            #pragma unroll
            for (int n = 0; n < 4; ++n) {
                float za = acc[m][n][j] + baj[j];
                float zb = acc[m + 2][n][j] + bbj[j];
                orow[n * 16] = za / (1.0f + expf(-zb));
            }
        }
    }
}

extern "C" void kernel_launch(void* const* d_in, const int* in_sizes, int n_in,
                              void* d_out, int out_size, void* d_ws, size_t ws_size,
                              hipStream_t stream) {
    (void)in_sizes; (void)n_in; (void)out_size; (void)ws_size;
    const float* u      = (const float*)d_in[0];
    const float* log_dt = (const float*)d_in[1];
    const float* Cr     = (const float*)d_in[2];
    const float* Ci     = (const float*)d_in[3];
    const float* lar    = (const float*)d_in[4];
    const float* aim    = (const float*)d_in[5];
    const float* Dvec   = (const float*)d_in[6];
    const float* W      = (const float*)d_in[7];
    const float* bo     = (const float*)d_in[8];
    float* out = (float*)d_out;

    char* ws = (char*)d_ws;
    float*          w32c = (float*)ws;                          // 64 KB
    unsigned short* Mp   = (unsigned short*)(ws + 65536);       // 1 MB
    unsigned short* Em   = (unsigned short*)(ws + 1114112);     // 1 MB
    unsigned short* Tm   = (unsigned short*)(ws + 2162688);     // 512 KB
    unsigned short* Wbf  = (unsigned short*)(ws + 2686976);     // 256 KB
    unsigned short* ybf  = (unsigned short*)(ws + 2949120);     // 32 MB

    precompute_kernel<<<dim3(NH), dim3(64), 0, stream>>>(
        log_dt, Cr, Ci, lar, aim, Dvec, w32c, Mp, Em, Tm, W, Wbf);
    scan_mfma_kernel<<<dim3(NB * NH), dim3(256), 0, stream>>>(u, w32c, Mp, Tm, Em, ybf);
    gemm_glu_mfma<<<dim3(NL / 64, NB), dim3(512), 0, stream>>>(ybf, Wbf, bo, out);
}

// Round 14
// 95.640 us; speedup vs baseline: 1.4930x; 1.0428x over previous
//
#include <hip/hip_runtime.h>

#define NB 16
#define NH 256
#define NL 4096
#define NN 32

typedef short s8v __attribute__((ext_vector_type(8)));
typedef float f4v __attribute__((ext_vector_type(4)));
typedef unsigned short u8h __attribute__((ext_vector_type(8)));

__device__ __forceinline__ unsigned short f2bf(float x) {
    unsigned int u = __float_as_uint(x);
    unsigned int r = u + 0x7FFFu + ((u >> 16) & 1u);
    return (unsigned short)(r >> 16);
}
__device__ __forceinline__ float bf2f(unsigned short b) {
    return __uint_as_float(((unsigned int)b) << 16);
}

// ---------- merged precompute (unchanged) ----------
__global__ __launch_bounds__(64) void precompute_kernel(
        const float* __restrict__ log_dt,
        const float* __restrict__ Cr,
        const float* __restrict__ Ci,
        const float* __restrict__ lar,
        const float* __restrict__ aim,
        const float* __restrict__ Dvec,
        float* __restrict__ w32c,
        unsigned short* __restrict__ Mp,
        unsigned short* __restrict__ Em,
        unsigned short* __restrict__ Tm,
        const float* __restrict__ W,
        unsigned short* __restrict__ Wbf) {
    const int h = blockIdx.x;
    const int tid = threadIdx.x;
    __shared__ float sRe[32][33];
    __shared__ float sTd[32];
    __shared__ unsigned short sMp[64 * 32];
    __shared__ unsigned short sEm[32 * 64];

    if (tid < 32) {
        const int n = tid;
        const int idx = h * 32 + n;
        float dt = expf(log_dt[h]);
        float ar = -expf(lar[idx]);
        float ai = aim[idx];
        float dar = ar * dt, dai = ai * dt;
        float er = expf(dar);
        float wr = er * cosf(dai), wi = er * sinf(dai);
        float Er = wr - 1.0f, Ei = wi;
        float den = ar * ar + ai * ai;
        float fr = (Er * ar + Ei * ai) / den;
        float fi = (Ei * ar - Er * ai) / den;
        float cr = Cr[idx], ci = Ci[idx];
        float c2r = 2.0f * (cr * fr - ci * fi);
        float c2i = 2.0f * (cr * fi + ci * fr);
        float e32 = expf(32.0f * dar);
        w32c[h * 64 + 2 * n]     = e32 * cosf(32.0f * dai);
        w32c[h * 64 + 2 * n + 1] = e32 * sinf(32.0f * dai);
        float pr = 1.0f, pi = 0.0f;
        for (int e = 0; e < 32; ++e) {
            sMp[(2 * n) * 32 + (31 - e)]     = f2bf(pr);
            sMp[(2 * n + 1) * 32 + (31 - e)] = f2bf(pi);
            float npr = pr * wr - pi * wi;
            pi = fmaf(pr, wi, pi * wr);
            pr = npr;
        }
        float gr = c2r, gi = c2i;
        for (int e = 0; e <= 32; ++e) {
            if (e < 32) sRe[e][n] = gr;
            if (e >= 1) {
                sEm[(e - 1) * 64 + 2 * n]     = f2bf(gr);
                sEm[(e - 1) * 64 + 2 * n + 1] = f2bf(-gi);
            }
            float ngr = gr * wr - gi * wi;
            gi = fmaf(gr, wi, gi * wr);
            gr = ngr;
        }
    }
    __syncthreads();
    if (tid < 32) {
        float a = 0.0f;
        #pragma unroll
        for (int n = 0; n < 32; ++n) a += sRe[tid][n];
        sTd[tid] = a;
    }
    __syncthreads();
    const float dh = Dvec[h];
    unsigned short* tmh = Tm + h * 1024;
    for (int i = 0; i < 16; ++i) {
        int idx = tid * 16 + i;
        int j = idx >> 5, tt = idx & 31;
        float v = (j >= tt) ? sTd[j - tt] : 0.0f;
        if (j == tt) v += dh;
        tmh[idx] = f2bf(v);
    }
    uint4* mp4 = (uint4*)(Mp + h * 2048);
    uint4* em4 = (uint4*)(Em + h * 2048);
    const uint4* smp4 = (const uint4*)sMp;
    const uint4* sem4 = (const uint4*)sEm;
    #pragma unroll
    for (int k = 0; k < 4; ++k) {
        mp4[k * 64 + tid] = smp4[k * 64 + tid];
        em4[k * 64 + tid] = sem4[k * 64 + tid];
    }
    const int gidx = h * 64 + tid;
    #pragma unroll
    for (int k = 0; k < 2; ++k) {
        int i = gidx + k * (NH * 64);
        float4 v = ((const float4*)W)[i];
        ushort4 o;
        o.x = f2bf(v.x); o.y = f2bf(v.y); o.z = f2bf(v.z); o.w = f2bf(v.w);
        ((ushort4*)Wbf)[i] = o;
    }
}

// ---------- MFMA chunked scan: direct-from-global U fragments (no u LDS stage) ----------
__global__ __launch_bounds__(256) void scan_mfma_kernel(
        const float* __restrict__ u,
        const float* __restrict__ w32c,
        const unsigned short* __restrict__ Mp,
        const unsigned short* __restrict__ Tm,
        const unsigned short* __restrict__ Em,
        unsigned short* __restrict__ ybf) {
    const int bh = blockIdx.x;
    const int h = bh & (NH - 1);
    const int tid = threadIdx.x;
    const int lane = tid & 63;
    const int wv = tid >> 6;
    const int g = lane >> 4, c = lane & 15;

    __shared__ float ldsT[256];                               // [4 seg][32 n][2] f32
    __shared__ __align__(16) unsigned int ldsP[128 * 36];     // 18432 B

    // ---- U fragments straight from global (coalesced 2KB/wave), f32->bf16 in-reg ----
    s8v bu[2];
    #pragma unroll
    for (int ntl = 0; ntl < 2; ++ntl) {
        const float* usrc = u + (size_t)bh * NL + (((2 * wv + ntl) * 16 + c) << 5) + g * 8;
        float4 x0 = *(const float4*)usrc;
        float4 x1 = *(const float4*)(usrc + 4);
        s8v t;
        t[0] = (short)f2bf(x0.x); t[1] = (short)f2bf(x0.y);
        t[2] = (short)f2bf(x0.z); t[3] = (short)f2bf(x0.w);
        t[4] = (short)f2bf(x1.x); t[5] = (short)f2bf(x1.y);
        t[6] = (short)f2bf(x1.z); t[7] = (short)f2bf(x1.w);
        bu[ntl] = t;
    }

    const unsigned short* mph = Mp + h * 2048;
    f4v p1[4][2];
    #pragma unroll
    for (int mt = 0; mt < 4; ++mt) {
        s8v am = *(const s8v*)(mph + (mt * 16 + c) * 32 + g * 8);
        p1[mt][0] = (f4v){0.f,0.f,0.f,0.f};
        p1[mt][1] = (f4v){0.f,0.f,0.f,0.f};
        p1[mt][0] = __builtin_amdgcn_mfma_f32_16x16x32_bf16(am, bu[0], p1[mt][0], 0,0,0);
        p1[mt][1] = __builtin_amdgcn_mfma_f32_16x16x32_bf16(am, bu[1], p1[mt][1], 0,0,0);
    }
    #pragma unroll
    for (int mt = 0; mt < 4; ++mt)
        #pragma unroll
        for (int ntl = 0; ntl < 2; ++ntl) {
            const int chunk = (2 * wv + ntl) * 16 + c;
            f4v v = p1[mt][ntl];
            unsigned int lo = (unsigned int)f2bf(v[0]) | ((unsigned int)f2bf(v[1]) << 16);
            unsigned int hi = (unsigned int)f2bf(v[2]) | ((unsigned int)f2bf(v[3]) << 16);
            *(uint2*)&ldsP[chunk * 36 + mt * 8 + 2 * g] = make_uint2(lo, hi);
        }
    __syncthreads();

    // ---- phase B1: 4 segments x 32 chunks on 2 waves; local exclusive scans ----
    float wr_b = 0.f, wi_b = 0.f;
    if (tid < 128) {
        const int n = tid & 31, seg = tid >> 5;
        wr_b = w32c[h * 64 + 2 * n];
        wi_b = w32c[h * 64 + 2 * n + 1];
        float sr = 0.f, si = 0.f;
        const int base = seg * 32;
        for (int t = 0; t < 32; ++t) {
            const int chunk = base + t;
            unsigned int pv = ldsP[chunk * 36 + n];
            ldsP[chunk * 36 + n] =
                (unsigned int)f2bf(sr) | ((unsigned int)f2bf(si) << 16);
            float Pr = bf2f((unsigned short)(pv & 0xFFFF));
            float Pi = bf2f((unsigned short)(pv >> 16));
            float nsr = fmaf(wr_b, sr, fmaf(-wi_b, si, Pr));
            float nsi = fmaf(wr_b, si, fmaf(wi_b, sr, Pi));
            sr = nsr; si = nsi;
        }
        *(float2*)&ldsT[(seg * 32 + n) * 2] = make_float2(sr, si);
    }
    __syncthreads();
    // ---- phase B2: fixup with cross-segment prefix Q ----
    if (tid < 128) {
        const int n = tid & 31, seg = tid >> 5;
        if (seg > 0) {
            float qr = wr_b, qi = wi_b;
            #pragma unroll
            for (int sq = 0; sq < 5; ++sq) {
                float nr = qr * qr - qi * qi;
                float ni = 2.0f * qr * qi;
                qr = nr; qi = ni;
            }
            float Qr = 0.f, Qi = 0.f;
            #pragma unroll
            for (int sp = 0; sp < 3; ++sp) {
                float2 Tv = *(const float2*)&ldsT[(sp * 32 + n) * 2];
                if (sp < seg) {
                    float nQr = fmaf(qr, Qr, fmaf(-qi, Qi, Tv.x));
                    float nQi = fmaf(qr, Qi, fmaf(qi, Qr, Tv.y));
                    Qr = nQr; Qi = nQi;
                }
            }
            float gr = Qr, gi = Qi;
            const int base = seg * 32;
            for (int t = 0; t < 32; ++t) {
                const int chunk = base + t;
                unsigned int sv = ldsP[chunk * 36 + n];
                float fr2 = bf2f((unsigned short)(sv & 0xFFFF)) + gr;
                float fi2 = bf2f((unsigned short)(sv >> 16)) + gi;
                ldsP[chunk * 36 + n] =
                    (unsigned int)f2bf(fr2) | ((unsigned int)f2bf(fi2) << 16);
                float ngr = wr_b * gr - wi_b * gi;
                float ngi = fmaf(wr_b, gi, wi_b * gr);
                gr = ngr; gi = ngi;
            }
        }
    }
    __syncthreads();

    const unsigned short* tmh = Tm + h * 1024;
    const unsigned short* emh = Em + h * 2048;
    const unsigned short* sbase = (const unsigned short*)ldsP;
    f4v a2[2][2];
    #pragma unroll
    for (int mt = 0; mt < 2; ++mt) {
        a2[mt][0] = (f4v){0.f,0.f,0.f,0.f};
        a2[mt][1] = (f4v){0.f,0.f,0.f,0.f};
        s8v at = *(const s8v*)(tmh + (mt * 16 + c) * 32 + g * 8);
        a2[mt][0] = __builtin_amdgcn_mfma_f32_16x16x32_bf16(at, bu[0], a2[mt][0], 0,0,0);
        a2[mt][1] = __builtin_amdgcn_mfma_f32_16x16x32_bf16(at, bu[1], a2[mt][1], 0,0,0);
    }
    #pragma unroll
    for (int ksub = 0; ksub < 2; ++ksub) {
        s8v bs[2];
        #pragma unroll
        for (int ntl = 0; ntl < 2; ++ntl) {
            const int chunk = (2 * wv + ntl) * 16 + c;
            bs[ntl] = *(const s8v*)(sbase + chunk * 72 + ksub * 32 + g * 8);
        }
        #pragma unroll
        for (int mt = 0; mt < 2; ++mt) {
            s8v ae = *(const s8v*)(emh + (mt * 16 + c) * 64 + ksub * 32 + g * 8);
            a2[mt][0] = __builtin_amdgcn_mfma_f32_16x16x32_bf16(ae, bs[0], a2[mt][0], 0,0,0);
            a2[mt][1] = __builtin_amdgcn_mfma_f32_16x16x32_bf16(ae, bs[1], a2[mt][1], 0,0,0);
        }
    }

    unsigned short* yrow = ybf + (size_t)bh * NL;
    #pragma unroll
    for (int mt = 0; mt < 2; ++mt)
        #pragma unroll
        for (int ntl = 0; ntl < 2; ++ntl) {
            const int chunk = (2 * wv + ntl) * 16 + c;
            f4v v = a2[mt][ntl];
            unsigned short gs[4];
            #pragma unroll
            for (int r = 0; r < 4; ++r) {
                float x = v[r];
                gs[r] = f2bf(0.5f * x * (1.0f + erff(x * 0.70710678118654752f)));
            }
            unsigned int lo = (unsigned int)gs[0] | ((unsigned int)gs[1] << 16);
            unsigned int hi = (unsigned int)gs[2] | ((unsigned int)gs[3] << 16);
            *(uint2*)(yrow + chunk * 32 + mt * 16 + 4 * g) = make_uint2(lo, hi);
        }
}

// ---------------- MFMA GEMM + GLU: full-K LDS, XOR-swizzle, fast sigmoid ----------------
__global__ __launch_bounds__(512) void gemm_glu_mfma(
        const unsigned short* __restrict__ ybf,
        const unsigned short* __restrict__ Wbf,
        const float* __restrict__ bo,
        float* __restrict__ out) {
    const int l0 = blockIdx.x * 64;
    const int b  = blockIdx.y;
    const int tid = threadIdx.x;
    const int lane = tid & 63;
    const int wv = tid >> 6;            // 0..7
    const int g = lane >> 4, c = lane & 15;

    __shared__ __align__(16) unsigned int ldsY[64 * 132];  // 33792 B

    // ---- stage: y[b, 0..256, l0..l0+64) transposed+packed, swizzled ----
    {
        const int r  = tid >> 1;
        const int hh = tid & 1;
        const int kp = r >> 1, hb = r & 1;
        const int kps = kp ^ (hh << 4);
        const unsigned short* ysrc = ybf + ((size_t)b * NH + r) * NL + l0 + hh * 32;
        uint4 v0 = ((const uint4*)ysrc)[0];
        uint4 v1 = ((const uint4*)ysrc)[1];
        uint4 v2 = ((const uint4*)ysrc)[2];
        uint4 v3 = ((const uint4*)ysrc)[3];
        unsigned short* lds16 = (unsigned short*)ldsY;
        const int base16 = ((hh * 32) * 132 + kps) * 2 + hb;
        u8h a0 = *(const u8h*)&v0, a1 = *(const u8h*)&v1;
        u8h a2 = *(const u8h*)&v2, a3 = *(const u8h*)&v3;
        #pragma unroll
        for (int j = 0; j < 8; ++j) {
            lds16[base16 + (j)      * 264] = a0[j];
            lds16[base16 + (j + 8)  * 264] = a1[j];
            lds16[base16 + (j + 16) * 264] = a2[j];
            lds16[base16 + (j + 24) * 264] = a3[j];
        }
    }
    __syncthreads();

    f4v acc[4][4];
    #pragma unroll
    for (int m = 0; m < 4; ++m)
        #pragma unroll
        for (int n = 0; n < 4; ++n)
            acc[m][n] = (f4v){0.f, 0.f, 0.f, 0.f};

    int wrow[4];
    wrow[0] = wv * 32 + c;
    wrow[1] = wrow[0] + 16;
    wrow[2] = wrow[0] + 256;
    wrow[3] = wrow[1] + 256;

    s8v afr[4];
    #pragma unroll
    for (int m = 0; m < 4; ++m)
        afr[m] = *(const s8v*)(Wbf + wrow[m] * NH + g * 8);

    #pragma unroll
    for (int ks = 0; ks < 8; ++ks) {
        s8v acur[4];
        #pragma unroll
        for (int m = 0; m < 4; ++m) acur[m] = afr[m];
        if (ks < 7) {
            #pragma unroll
            for (int m = 0; m < 4; ++m)
                afr[m] = *(const s8v*)(Wbf + wrow[m] * NH + (ks + 1) * 32 + g * 8);
        }
        s8v bfr[4];
        #pragma unroll
        for (int n = 0; n < 4; ++n) {
            const int colb = (ks * 16 + g * 4) ^ ((n >> 1) << 4);
            bfr[n] = *(const s8v*)&ldsY[(n * 16 + c) * 132 + colb];
        }
        #pragma unroll
        for (int m = 0; m < 4; ++m)
            #pragma unroll
            for (int n = 0; n < 4; ++n)
                acc[m][n] = __builtin_amdgcn_mfma_f32_16x16x32_bf16(
                    acur[m], bfr[n], acc[m][n], 0, 0, 0);
    }

    // ---- epilogue: GLU with __expf + rcp (|Dout| <= ~1e-5, analytically safe) ----
    #pragma unroll
    for (int m = 0; m < 2; ++m) {
        const int o0 = wv * 32 + m * 16 + g * 4;
        float4 ba = *(const float4*)(bo + o0);
        float4 bb = *(const float4*)(bo + NH + o0);
        const float baj[4] = {ba.x, ba.y, ba.z, ba.w};
        const float bbj[4] = {bb.x, bb.y, bb.z, bb.w};
        #pragma unroll
        for (int j = 0; j < 4; ++j) {
            float* orow = out + ((size_t)(b * NH + o0 + j)) * NL + l0 + c;
            #pragma unroll
            for (int n = 0; n < 4; ++n) {
                float za = acc[m][n][j] + baj[j];
                float zb = acc[m + 2][n][j] + bbj[j];
                float s = __builtin_amdgcn_rcpf(1.0f + __expf(-zb));
                orow[n * 16] = za * s;
            }
        }
    }
}

extern "C" void kernel_launch(void* const* d_in, const int* in_sizes, int n_in,
                              void* d_out, int out_size, void* d_ws, size_t ws_size,
                              hipStream_t stream) {
    (void)in_sizes; (void)n_in; (void)out_size; (void)ws_size;
    const float* u      = (const float*)d_in[0];
    const float* log_dt = (const float*)d_in[1];
    const float* Cr     = (const float*)d_in[2];
    const float* Ci     = (const float*)d_in[3];
    const float* lar    = (const float*)d_in[4];
    const float* aim    = (const float*)d_in[5];
    const float* Dvec   = (const float*)d_in[6];
    const float* W      = (const float*)d_in[7];
    const float* bo     = (const float*)d_in[8];
    float* out = (float*)d_out;

    char* ws = (char*)d_ws;
    float*          w32c = (float*)ws;                          // 64 KB
    unsigned short* Mp   = (unsigned short*)(ws + 65536);       // 1 MB
    unsigned short* Em   = (unsigned short*)(ws + 1114112);     // 1 MB
    unsigned short* Tm   = (unsigned short*)(ws + 2162688);     // 512 KB
    unsigned short* Wbf  = (unsigned short*)(ws + 2686976);     // 256 KB
    unsigned short* ybf  = (unsigned short*)(ws + 2949120);     // 32 MB

    precompute_kernel<<<dim3(NH), dim3(64), 0, stream>>>(
        log_dt, Cr, Ci, lar, aim, Dvec, w32c, Mp, Em, Tm, W, Wbf);
    scan_mfma_kernel<<<dim3(NB * NH), dim3(256), 0, stream>>>(u, w32c, Mp, Tm, Em, ybf);
    gemm_glu_mfma<<<dim3(NL / 64, NB), dim3(512), 0, stream>>>(ybf, Wbf, bo, out);
}

// Round 15
// 93.886 us; speedup vs baseline: 1.5209x; 1.0187x over previous
//
#include <hip/hip_runtime.h>

#define NB 16
#define NH 256
#define NL 4096
#define NN 32

typedef short s8v __attribute__((ext_vector_type(8)));
typedef float f4v __attribute__((ext_vector_type(4)));
typedef unsigned short u8h __attribute__((ext_vector_type(8)));

__device__ __forceinline__ unsigned short f2bf(float x) {
    unsigned int u = __float_as_uint(x);
    unsigned int r = u + 0x7FFFu + ((u >> 16) & 1u);
    return (unsigned short)(r >> 16);
}
__device__ __forceinline__ float bf2f(unsigned short b) {
    return __uint_as_float(((unsigned int)b) << 16);
}
// HW pack: two f32 -> one u32 holding (lo=src0, hi=src1) as bf16 (RNE). T12/m240.
__device__ __forceinline__ unsigned int cvt_pk_bf16(float lo, float hi) {
    unsigned int r;
    asm("v_cvt_pk_bf16_f32 %0, %1, %2" : "=v"(r) : "v"(lo), "v"(hi));
    return r;
}

// ---------- merged precompute (unchanged) ----------
__global__ __launch_bounds__(64) void precompute_kernel(
        const float* __restrict__ log_dt,
        const float* __restrict__ Cr,
        const float* __restrict__ Ci,
        const float* __restrict__ lar,
        const float* __restrict__ aim,
        const float* __restrict__ Dvec,
        float* __restrict__ w32c,
        unsigned short* __restrict__ Mp,
        unsigned short* __restrict__ Em,
        unsigned short* __restrict__ Tm,
        const float* __restrict__ W,
        unsigned short* __restrict__ Wbf) {
    const int h = blockIdx.x;
    const int tid = threadIdx.x;
    __shared__ float sRe[32][33];
    __shared__ float sTd[32];
    __shared__ unsigned short sMp[64 * 32];
    __shared__ unsigned short sEm[32 * 64];

    if (tid < 32) {
        const int n = tid;
        const int idx = h * 32 + n;
        float dt = expf(log_dt[h]);
        float ar = -expf(lar[idx]);
        float ai = aim[idx];
        float dar = ar * dt, dai = ai * dt;
        float er = expf(dar);
        float wr = er * cosf(dai), wi = er * sinf(dai);
        float Er = wr - 1.0f, Ei = wi;
        float den = ar * ar + ai * ai;
        float fr = (Er * ar + Ei * ai) / den;
        float fi = (Ei * ar - Er * ai) / den;
        float cr = Cr[idx], ci = Ci[idx];
        float c2r = 2.0f * (cr * fr - ci * fi);
        float c2i = 2.0f * (cr * fi + ci * fr);
        float e32 = expf(32.0f * dar);
        w32c[h * 64 + 2 * n]     = e32 * cosf(32.0f * dai);
        w32c[h * 64 + 2 * n + 1] = e32 * sinf(32.0f * dai);
        float pr = 1.0f, pi = 0.0f;
        for (int e = 0; e < 32; ++e) {
            sMp[(2 * n) * 32 + (31 - e)]     = f2bf(pr);
            sMp[(2 * n + 1) * 32 + (31 - e)] = f2bf(pi);
            float npr = pr * wr - pi * wi;
            pi = fmaf(pr, wi, pi * wr);
            pr = npr;
        }
        float gr = c2r, gi = c2i;
        for (int e = 0; e <= 32; ++e) {
            if (e < 32) sRe[e][n] = gr;
            if (e >= 1) {
                sEm[(e - 1) * 64 + 2 * n]     = f2bf(gr);
                sEm[(e - 1) * 64 + 2 * n + 1] = f2bf(-gi);
            }
            float ngr = gr * wr - gi * wi;
            gi = fmaf(gr, wi, gi * wr);
            gr = ngr;
        }
    }
    __syncthreads();
    if (tid < 32) {
        float a = 0.0f;
        #pragma unroll
        for (int n = 0; n < 32; ++n) a += sRe[tid][n];
        sTd[tid] = a;
    }
    __syncthreads();
    const float dh = Dvec[h];
    unsigned short* tmh = Tm + h * 1024;
    for (int i = 0; i < 16; ++i) {
        int idx = tid * 16 + i;
        int j = idx >> 5, tt = idx & 31;
        float v = (j >= tt) ? sTd[j - tt] : 0.0f;
        if (j == tt) v += dh;
        tmh[idx] = f2bf(v);
    }
    uint4* mp4 = (uint4*)(Mp + h * 2048);
    uint4* em4 = (uint4*)(Em + h * 2048);
    const uint4* smp4 = (const uint4*)sMp;
    const uint4* sem4 = (const uint4*)sEm;
    #pragma unroll
    for (int k = 0; k < 4; ++k) {
        mp4[k * 64 + tid] = smp4[k * 64 + tid];
        em4[k * 64 + tid] = sem4[k * 64 + tid];
    }
    const int gidx = h * 64 + tid;
    #pragma unroll
    for (int k = 0; k < 2; ++k) {
        int i = gidx + k * (NH * 64);
        float4 v = ((const float4*)W)[i];
        ushort4 o;
        o.x = f2bf(v.x); o.y = f2bf(v.y); o.z = f2bf(v.z); o.w = f2bf(v.w);
        ((ushort4*)Wbf)[i] = o;
    }
}

// ---------- MFMA chunked scan: hw cvt_pk for all f32->bf16 pair packs ----------
__global__ __launch_bounds__(256) void scan_mfma_kernel(
        const float* __restrict__ u,
        const float* __restrict__ w32c,
        const unsigned short* __restrict__ Mp,
        const unsigned short* __restrict__ Tm,
        const unsigned short* __restrict__ Em,
        unsigned short* __restrict__ ybf) {
    const int bh = blockIdx.x;
    const int h = bh & (NH - 1);
    const int tid = threadIdx.x;
    const int lane = tid & 63;
    const int wv = tid >> 6;
    const int g = lane >> 4, c = lane & 15;

    __shared__ float ldsT[256];                               // [4 seg][32 n][2] f32
    __shared__ __align__(16) unsigned int ldsP[128 * 36];     // 18432 B

    // ---- U fragments straight from global, pack via cvt_pk ----
    s8v bu[2];
    #pragma unroll
    for (int ntl = 0; ntl < 2; ++ntl) {
        const float* usrc = u + (size_t)bh * NL + (((2 * wv + ntl) * 16 + c) << 5) + g * 8;
        float4 x0 = *(const float4*)usrc;
        float4 x1 = *(const float4*)(usrc + 4);
        union { unsigned int w[4]; s8v v; } cv;
        cv.w[0] = cvt_pk_bf16(x0.x, x0.y);
        cv.w[1] = cvt_pk_bf16(x0.z, x0.w);
        cv.w[2] = cvt_pk_bf16(x1.x, x1.y);
        cv.w[3] = cvt_pk_bf16(x1.z, x1.w);
        bu[ntl] = cv.v;
    }

    const unsigned short* mph = Mp + h * 2048;
    f4v p1[4][2];
    #pragma unroll
    for (int mt = 0; mt < 4; ++mt) {
        s8v am = *(const s8v*)(mph + (mt * 16 + c) * 32 + g * 8);
        p1[mt][0] = (f4v){0.f,0.f,0.f,0.f};
        p1[mt][1] = (f4v){0.f,0.f,0.f,0.f};
        p1[mt][0] = __builtin_amdgcn_mfma_f32_16x16x32_bf16(am, bu[0], p1[mt][0], 0,0,0);
        p1[mt][1] = __builtin_amdgcn_mfma_f32_16x16x32_bf16(am, bu[1], p1[mt][1], 0,0,0);
    }
    #pragma unroll
    for (int mt = 0; mt < 4; ++mt)
        #pragma unroll
        for (int ntl = 0; ntl < 2; ++ntl) {
            const int chunk = (2 * wv + ntl) * 16 + c;
            f4v v = p1[mt][ntl];
            unsigned int lo = cvt_pk_bf16(v[0], v[1]);
            unsigned int hi = cvt_pk_bf16(v[2], v[3]);
            *(uint2*)&ldsP[chunk * 36 + mt * 8 + 2 * g] = make_uint2(lo, hi);
        }
    __syncthreads();

    // ---- phase B1: 4 segments x 32 chunks on 2 waves; local exclusive scans ----
    float wr_b = 0.f, wi_b = 0.f;
    if (tid < 128) {
        const int n = tid & 31, seg = tid >> 5;
        wr_b = w32c[h * 64 + 2 * n];
        wi_b = w32c[h * 64 + 2 * n + 1];
        float sr = 0.f, si = 0.f;
        const int base = seg * 32;
        for (int t = 0; t < 32; ++t) {
            const int chunk = base + t;
            unsigned int pv = ldsP[chunk * 36 + n];
            ldsP[chunk * 36 + n] = cvt_pk_bf16(sr, si);   // exclusive local
            float Pr = bf2f((unsigned short)(pv & 0xFFFF));
            float Pi = bf2f((unsigned short)(pv >> 16));
            float nsr = fmaf(wr_b, sr, fmaf(-wi_b, si, Pr));
            float nsi = fmaf(wr_b, si, fmaf(wi_b, sr, Pi));
            sr = nsr; si = nsi;
        }
        *(float2*)&ldsT[(seg * 32 + n) * 2] = make_float2(sr, si);
    }
    __syncthreads();
    // ---- phase B2: fixup with cross-segment prefix Q ----
    if (tid < 128) {
        const int n = tid & 31, seg = tid >> 5;
        if (seg > 0) {
            float qr = wr_b, qi = wi_b;
            #pragma unroll
            for (int sq = 0; sq < 5; ++sq) {
                float nr = qr * qr - qi * qi;
                float ni = 2.0f * qr * qi;
                qr = nr; qi = ni;
            }
            float Qr = 0.f, Qi = 0.f;
            #pragma unroll
            for (int sp = 0; sp < 3; ++sp) {
                float2 Tv = *(const float2*)&ldsT[(sp * 32 + n) * 2];
                if (sp < seg) {
                    float nQr = fmaf(qr, Qr, fmaf(-qi, Qi, Tv.x));
                    float nQi = fmaf(qr, Qi, fmaf(qi, Qr, Tv.y));
                    Qr = nQr; Qi = nQi;
                }
            }
            float gr = Qr, gi = Qi;
            const int base = seg * 32;
            for (int t = 0; t < 32; ++t) {
                const int chunk = base + t;
                unsigned int sv = ldsP[chunk * 36 + n];
                float fr2 = bf2f((unsigned short)(sv & 0xFFFF)) + gr;
                float fi2 = bf2f((unsigned short)(sv >> 16)) + gi;
                ldsP[chunk * 36 + n] = cvt_pk_bf16(fr2, fi2);
                float ngr = wr_b * gr - wi_b * gi;
                float ngi = fmaf(wr_b, gi, wi_b * gr);
                gr = ngr; gi = ngi;
            }
        }
    }
    __syncthreads();

    const unsigned short* tmh = Tm + h * 1024;
    const unsigned short* emh = Em + h * 2048;
    const unsigned short* sbase = (const unsigned short*)ldsP;
    f4v a2[2][2];
    #pragma unroll
    for (int mt = 0; mt < 2; ++mt) {
        a2[mt][0] = (f4v){0.f,0.f,0.f,0.f};
        a2[mt][1] = (f4v){0.f,0.f,0.f,0.f};
        s8v at = *(const s8v*)(tmh + (mt * 16 + c) * 32 + g * 8);
        a2[mt][0] = __builtin_amdgcn_mfma_f32_16x16x32_bf16(at, bu[0], a2[mt][0], 0,0,0);
        a2[mt][1] = __builtin_amdgcn_mfma_f32_16x16x32_bf16(at, bu[1], a2[mt][1], 0,0,0);
    }
    #pragma unroll
    for (int ksub = 0; ksub < 2; ++ksub) {
        s8v bs[2];
        #pragma unroll
        for (int ntl = 0; ntl < 2; ++ntl) {
            const int chunk = (2 * wv + ntl) * 16 + c;
            bs[ntl] = *(const s8v*)(sbase + chunk * 72 + ksub * 32 + g * 8);
        }
        #pragma unroll
        for (int mt = 0; mt < 2; ++mt) {
            s8v ae = *(const s8v*)(emh + (mt * 16 + c) * 64 + ksub * 32 + g * 8);
            a2[mt][0] = __builtin_amdgcn_mfma_f32_16x16x32_bf16(ae, bs[0], a2[mt][0], 0,0,0);
            a2[mt][1] = __builtin_amdgcn_mfma_f32_16x16x32_bf16(ae, bs[1], a2[mt][1], 0,0,0);
        }
    }

    unsigned short* yrow = ybf + (size_t)bh * NL;
    #pragma unroll
    for (int mt = 0; mt < 2; ++mt)
        #pragma unroll
        for (int ntl = 0; ntl < 2; ++ntl) {
            const int chunk = (2 * wv + ntl) * 16 + c;
            f4v v = a2[mt][ntl];
            float gv[4];
            #pragma unroll
            for (int r = 0; r < 4; ++r) {
                float x = v[r];
                gv[r] = 0.5f * x * (1.0f + erff(x * 0.70710678118654752f));
            }
            unsigned int lo = cvt_pk_bf16(gv[0], gv[1]);
            unsigned int hi = cvt_pk_bf16(gv[2], gv[3]);
            *(uint2*)(yrow + chunk * 32 + mt * 16 + 4 * g) = make_uint2(lo, hi);
        }
}

// ---------------- MFMA GEMM + GLU: full-K LDS, XOR-swizzle, fast sigmoid (unchanged) ----------------
__global__ __launch_bounds__(512) void gemm_glu_mfma(
        const unsigned short* __restrict__ ybf,
        const unsigned short* __restrict__ Wbf,
        const float* __restrict__ bo,
        float* __restrict__ out) {
    const int l0 = blockIdx.x * 64;
    const int b  = blockIdx.y;
    const int tid = threadIdx.x;
    const int lane = tid & 63;
    const int wv = tid >> 6;            // 0..7
    const int g = lane >> 4, c = lane & 15;

    __shared__ __align__(16) unsigned int ldsY[64 * 132];  // 33792 B

    {
        const int r  = tid >> 1;
        const int hh = tid & 1;
        const int kp = r >> 1, hb = r & 1;
        const int kps = kp ^ (hh << 4);
        const unsigned short* ysrc = ybf + ((size_t)b * NH + r) * NL + l0 + hh * 32;
        uint4 v0 = ((const uint4*)ysrc)[0];
        uint4 v1 = ((const uint4*)ysrc)[1];
        uint4 v2 = ((const uint4*)ysrc)[2];
        uint4 v3 = ((const uint4*)ysrc)[3];
        unsigned short* lds16 = (unsigned short*)ldsY;
        const int base16 = ((hh * 32) * 132 + kps) * 2 + hb;
        u8h a0 = *(const u8h*)&v0, a1 = *(const u8h*)&v1;
        u8h a2 = *(const u8h*)&v2, a3 = *(const u8h*)&v3;
        #pragma unroll
        for (int j = 0; j < 8; ++j) {
            lds16[base16 + (j)      * 264] = a0[j];
            lds16[base16 + (j + 8)  * 264] = a1[j];
            lds16[base16 + (j + 16) * 264] = a2[j];
            lds16[base16 + (j + 24) * 264] = a3[j];
        }
    }
    __syncthreads();

    f4v acc[4][4];
    #pragma unroll
    for (int m = 0; m < 4; ++m)
        #pragma unroll
        for (int n = 0; n < 4; ++n)
            acc[m][n] = (f4v){0.f, 0.f, 0.f, 0.f};

    int wrow[4];
    wrow[0] = wv * 32 + c;
    wrow[1] = wrow[0] + 16;
    wrow[2] = wrow[0] + 256;
    wrow[3] = wrow[1] + 256;

    s8v afr[4];
    #pragma unroll
    for (int m = 0; m < 4; ++m)
        afr[m] = *(const s8v*)(Wbf + wrow[m] * NH + g * 8);

    #pragma unroll
    for (int ks = 0; ks < 8; ++ks) {
        s8v acur[4];
        #pragma unroll
        for (int m = 0; m < 4; ++m) acur[m] = afr[m];
        if (ks < 7) {
            #pragma unroll
            for (int m = 0; m < 4; ++m)
                afr[m] = *(const s8v*)(Wbf + wrow[m] * NH + (ks + 1) * 32 + g * 8);
        }
        s8v bfr[4];
        #pragma unroll
        for (int n = 0; n < 4; ++n) {
            const int colb = (ks * 16 + g * 4) ^ ((n >> 1) << 4);
            bfr[n] = *(const s8v*)&ldsY[(n * 16 + c) * 132 + colb];
        }
        #pragma unroll
        for (int m = 0; m < 4; ++m)
            #pragma unroll
            for (int n = 0; n < 4; ++n)
                acc[m][n] = __builtin_amdgcn_mfma_f32_16x16x32_bf16(
                    acur[m], bfr[n], acc[m][n], 0, 0, 0);
    }

    #pragma unroll
    for (int m = 0; m < 2; ++m) {
        const int o0 = wv * 32 + m * 16 + g * 4;
        float4 ba = *(const float4*)(bo + o0);
        float4 bb = *(const float4*)(bo + NH + o0);
        const float baj[4] = {ba.x, ba.y, ba.z, ba.w};
        const float bbj[4] = {bb.x, bb.y, bb.z, bb.w};
        #pragma unroll
        for (int j = 0; j < 4; ++j) {
            float* orow = out + ((size_t)(b * NH + o0 + j)) * NL + l0 + c;
            #pragma unroll
            for (int n = 0; n < 4; ++n) {
                float za = acc[m][n][j] + baj[j];
                float zb = acc[m + 2][n][j] + bbj[j];
                float s = __builtin_amdgcn_rcpf(1.0f + __expf(-zb));
                orow[n * 16] = za * s;
            }
        }
    }
}

extern "C" void kernel_launch(void* const* d_in, const int* in_sizes, int n_in,
                              void* d_out, int out_size, void* d_ws, size_t ws_size,
                              hipStream_t stream) {
    (void)in_sizes; (void)n_in; (void)out_size; (void)ws_size;
    const float* u      = (const float*)d_in[0];
    const float* log_dt = (const float*)d_in[1];
    const float* Cr     = (const float*)d_in[2];
    const float* Ci     = (const float*)d_in[3];
    const float* lar    = (const float*)d_in[4];
    const float* aim    = (const float*)d_in[5];
    const float* Dvec   = (const float*)d_in[6];
    const float* W      = (const float*)d_in[7];
    const float* bo     = (const float*)d_in[8];
    float* out = (float*)d_out;

    char* ws = (char*)d_ws;
    float*          w32c = (float*)ws;                          // 64 KB
    unsigned short* Mp   = (unsigned short*)(ws + 65536);       // 1 MB
    unsigned short* Em   = (unsigned short*)(ws + 1114112);     // 1 MB
    unsigned short* Tm   = (unsigned short*)(ws + 2162688);     // 512 KB
    unsigned short* Wbf  = (unsigned short*)(ws + 2686976);     // 256 KB
    unsigned short* ybf  = (unsigned short*)(ws + 2949120);     // 32 MB

    precompute_kernel<<<dim3(NH), dim3(64), 0, stream>>>(
        log_dt, Cr, Ci, lar, aim, Dvec, w32c, Mp, Em, Tm, W, Wbf);
    scan_mfma_kernel<<<dim3(NB * NH), dim3(256), 0, stream>>>(u, w32c, Mp, Tm, Em, ybf);
    gemm_glu_mfma<<<dim3(NL / 64, NB), dim3(512), 0, stream>>>(ybf, Wbf, bo, out);
}

// Round 16
// 87.686 us; speedup vs baseline: 1.6284x; 1.0707x over previous
//
#include <hip/hip_runtime.h>

#define NB 16
#define NH 256
#define NL 4096
#define NN 32

typedef short s8v __attribute__((ext_vector_type(8)));
typedef float f4v __attribute__((ext_vector_type(4)));
typedef unsigned short u8h __attribute__((ext_vector_type(8)));

__device__ __forceinline__ unsigned short f2bf(float x) {
    unsigned int u = __float_as_uint(x);
    unsigned int r = u + 0x7FFFu + ((u >> 16) & 1u);
    return (unsigned short)(r >> 16);
}
__device__ __forceinline__ float bf2f(unsigned short b) {
    return __uint_as_float(((unsigned int)b) << 16);
}
// HW pack: two f32 -> one u32 holding (lo=src0, hi=src1) as bf16 (RNE).
__device__ __forceinline__ unsigned int cvt_pk_bf16(float lo, float hi) {
    unsigned int r;
    asm("v_cvt_pk_bf16_f32 %0, %1, %2" : "=v"(r) : "v"(lo), "v"(hi));
    return r;
}

// ---------- merged precompute (unchanged) ----------
__global__ __launch_bounds__(64) void precompute_kernel(
        const float* __restrict__ log_dt,
        const float* __restrict__ Cr,
        const float* __restrict__ Ci,
        const float* __restrict__ lar,
        const float* __restrict__ aim,
        const float* __restrict__ Dvec,
        float* __restrict__ w32c,
        unsigned short* __restrict__ Mp,
        unsigned short* __restrict__ Em,
        unsigned short* __restrict__ Tm,
        const float* __restrict__ W,
        unsigned short* __restrict__ Wbf) {
    const int h = blockIdx.x;
    const int tid = threadIdx.x;
    __shared__ float sRe[32][33];
    __shared__ float sTd[32];
    __shared__ unsigned short sMp[64 * 32];
    __shared__ unsigned short sEm[32 * 64];

    if (tid < 32) {
        const int n = tid;
        const int idx = h * 32 + n;
        float dt = expf(log_dt[h]);
        float ar = -expf(lar[idx]);
        float ai = aim[idx];
        float dar = ar * dt, dai = ai * dt;
        float er = expf(dar);
        float wr = er * cosf(dai), wi = er * sinf(dai);
        float Er = wr - 1.0f, Ei = wi;
        float den = ar * ar + ai * ai;
        float fr = (Er * ar + Ei * ai) / den;
        float fi = (Ei * ar - Er * ai) / den;
        float cr = Cr[idx], ci = Ci[idx];
        float c2r = 2.0f * (cr * fr - ci * fi);
        float c2i = 2.0f * (cr * fi + ci * fr);
        float e32 = expf(32.0f * dar);
        w32c[h * 64 + 2 * n]     = e32 * cosf(32.0f * dai);
        w32c[h * 64 + 2 * n + 1] = e32 * sinf(32.0f * dai);
        float pr = 1.0f, pi = 0.0f;
        for (int e = 0; e < 32; ++e) {
            sMp[(2 * n) * 32 + (31 - e)]     = f2bf(pr);
            sMp[(2 * n + 1) * 32 + (31 - e)] = f2bf(pi);
            float npr = pr * wr - pi * wi;
            pi = fmaf(pr, wi, pi * wr);
            pr = npr;
        }
        float gr = c2r, gi = c2i;
        for (int e = 0; e <= 32; ++e) {
            if (e < 32) sRe[e][n] = gr;
            if (e >= 1) {
                sEm[(e - 1) * 64 + 2 * n]     = f2bf(gr);
                sEm[(e - 1) * 64 + 2 * n + 1] = f2bf(-gi);
            }
            float ngr = gr * wr - gi * wi;
            gi = fmaf(gr, wi, gi * wr);
            gr = ngr;
        }
    }
    __syncthreads();
    if (tid < 32) {
        float a = 0.0f;
        #pragma unroll
        for (int n = 0; n < 32; ++n) a += sRe[tid][n];
        sTd[tid] = a;
    }
    __syncthreads();
    const float dh = Dvec[h];
    unsigned short* tmh = Tm + h * 1024;
    for (int i = 0; i < 16; ++i) {
        int idx = tid * 16 + i;
        int j = idx >> 5, tt = idx & 31;
        float v = (j >= tt) ? sTd[j - tt] : 0.0f;
        if (j == tt) v += dh;
        tmh[idx] = f2bf(v);
    }
    uint4* mp4 = (uint4*)(Mp + h * 2048);
    uint4* em4 = (uint4*)(Em + h * 2048);
    const uint4* smp4 = (const uint4*)sMp;
    const uint4* sem4 = (const uint4*)sEm;
    #pragma unroll
    for (int k = 0; k < 4; ++k) {
        mp4[k * 64 + tid] = smp4[k * 64 + tid];
        em4[k * 64 + tid] = sem4[k * 64 + tid];
    }
    const int gidx = h * 64 + tid;
    #pragma unroll
    for (int k = 0; k < 2; ++k) {
        int i = gidx + k * (NH * 64);
        float4 v = ((const float4*)W)[i];
        ushort4 o;
        o.x = f2bf(v.x); o.y = f2bf(v.y); o.z = f2bf(v.z); o.w = f2bf(v.w);
        ((ushort4*)Wbf)[i] = o;
    }
}

// ---------- MFMA chunked scan: 8-segment phase B on all 4 waves ----------
__global__ __launch_bounds__(256) void scan_mfma_kernel(
        const float* __restrict__ u,
        const float* __restrict__ w32c,
        const unsigned short* __restrict__ Mp,
        const unsigned short* __restrict__ Tm,
        const unsigned short* __restrict__ Em,
        unsigned short* __restrict__ ybf) {
    const int bh = blockIdx.x;
    const int h = bh & (NH - 1);
    const int tid = threadIdx.x;
    const int lane = tid & 63;
    const int wv = tid >> 6;
    const int g = lane >> 4, c = lane & 15;

    __shared__ float ldsT[512];                               // [8 seg][32 n][2] f32
    __shared__ __align__(16) unsigned int ldsP[128 * 36];     // 18432 B

    // ---- U fragments straight from global, pack via cvt_pk ----
    s8v bu[2];
    #pragma unroll
    for (int ntl = 0; ntl < 2; ++ntl) {
        const float* usrc = u + (size_t)bh * NL + (((2 * wv + ntl) * 16 + c) << 5) + g * 8;
        float4 x0 = *(const float4*)usrc;
        float4 x1 = *(const float4*)(usrc + 4);
        union { unsigned int w[4]; s8v v; } cv;
        cv.w[0] = cvt_pk_bf16(x0.x, x0.y);
        cv.w[1] = cvt_pk_bf16(x0.z, x0.w);
        cv.w[2] = cvt_pk_bf16(x1.x, x1.y);
        cv.w[3] = cvt_pk_bf16(x1.z, x1.w);
        bu[ntl] = cv.v;
    }

    const unsigned short* mph = Mp + h * 2048;
    f4v p1[4][2];
    #pragma unroll
    for (int mt = 0; mt < 4; ++mt) {
        s8v am = *(const s8v*)(mph + (mt * 16 + c) * 32 + g * 8);
        p1[mt][0] = (f4v){0.f,0.f,0.f,0.f};
        p1[mt][1] = (f4v){0.f,0.f,0.f,0.f};
        p1[mt][0] = __builtin_amdgcn_mfma_f32_16x16x32_bf16(am, bu[0], p1[mt][0], 0,0,0);
        p1[mt][1] = __builtin_amdgcn_mfma_f32_16x16x32_bf16(am, bu[1], p1[mt][1], 0,0,0);
    }
    #pragma unroll
    for (int mt = 0; mt < 4; ++mt)
        #pragma unroll
        for (int ntl = 0; ntl < 2; ++ntl) {
            const int chunk = (2 * wv + ntl) * 16 + c;
            f4v v = p1[mt][ntl];
            unsigned int lo = cvt_pk_bf16(v[0], v[1]);
            unsigned int hi = cvt_pk_bf16(v[2], v[3]);
            *(uint2*)&ldsP[chunk * 36 + mt * 8 + 2 * g] = make_uint2(lo, hi);
        }
    __syncthreads();

    // ---- phase B1: 8 segments x 16 chunks, ALL 256 threads; local exclusive scans ----
    {
        const int n = tid & 31, seg = tid >> 5;   // seg 0..7
        const float wr_b = w32c[h * 64 + 2 * n];
        const float wi_b = w32c[h * 64 + 2 * n + 1];
        float sr = 0.f, si = 0.f;
        const int base = seg * 16;
        for (int t = 0; t < 16; ++t) {
            const int chunk = base + t;
            unsigned int pv = ldsP[chunk * 36 + n];
            ldsP[chunk * 36 + n] = cvt_pk_bf16(sr, si);   // exclusive local
            float Pr = bf2f((unsigned short)(pv & 0xFFFF));
            float Pi = bf2f((unsigned short)(pv >> 16));
            float nsr = fmaf(wr_b, sr, fmaf(-wi_b, si, Pr));
            float nsi = fmaf(wr_b, si, fmaf(wi_b, sr, Pi));
            sr = nsr; si = nsi;
        }
        *(float2*)&ldsT[(seg * 32 + n) * 2] = make_float2(sr, si);  // T_seg
        __syncthreads();
        // ---- phase B2: fixup with cross-segment prefix Q (W512 = w32^16) ----
        if (seg > 0) {
            float qr = wr_b, qi = wi_b;
            #pragma unroll
            for (int sq = 0; sq < 4; ++sq) {
                float nr = qr * qr - qi * qi;
                float ni = 2.0f * qr * qi;
                qr = nr; qi = ni;
            }
            float Qr = 0.f, Qi = 0.f;
            #pragma unroll
            for (int sp = 0; sp < 7; ++sp) {
                float2 Tv = *(const float2*)&ldsT[(sp * 32 + n) * 2];
                if (sp < seg) {
                    float nQr = fmaf(qr, Qr, fmaf(-qi, Qi, Tv.x));
                    float nQi = fmaf(qr, Qi, fmaf(qi, Qr, Tv.y));
                    Qr = nQr; Qi = nQi;
                }
            }
            float gr = Qr, gi = Qi;
            for (int t = 0; t < 16; ++t) {
                const int chunk = base + t;
                unsigned int sv = ldsP[chunk * 36 + n];
                float fr2 = bf2f((unsigned short)(sv & 0xFFFF)) + gr;
                float fi2 = bf2f((unsigned short)(sv >> 16)) + gi;
                ldsP[chunk * 36 + n] = cvt_pk_bf16(fr2, fi2);
                float ngr = wr_b * gr - wi_b * gi;
                float ngi = fmaf(wr_b, gi, wi_b * gr);
                gr = ngr; gi = ngi;
            }
        }
    }
    __syncthreads();

    const unsigned short* tmh = Tm + h * 1024;
    const unsigned short* emh = Em + h * 2048;
    const unsigned short* sbase = (const unsigned short*)ldsP;
    f4v a2[2][2];
    #pragma unroll
    for (int mt = 0; mt < 2; ++mt) {
        a2[mt][0] = (f4v){0.f,0.f,0.f,0.f};
        a2[mt][1] = (f4v){0.f,0.f,0.f,0.f};
        s8v at = *(const s8v*)(tmh + (mt * 16 + c) * 32 + g * 8);
        a2[mt][0] = __builtin_amdgcn_mfma_f32_16x16x32_bf16(at, bu[0], a2[mt][0], 0,0,0);
        a2[mt][1] = __builtin_amdgcn_mfma_f32_16x16x32_bf16(at, bu[1], a2[mt][1], 0,0,0);
    }
    #pragma unroll
    for (int ksub = 0; ksub < 2; ++ksub) {
        s8v bs[2];
        #pragma unroll
        for (int ntl = 0; ntl < 2; ++ntl) {
            const int chunk = (2 * wv + ntl) * 16 + c;
            bs[ntl] = *(const s8v*)(sbase + chunk * 72 + ksub * 32 + g * 8);
        }
        #pragma unroll
        for (int mt = 0; mt < 2; ++mt) {
            s8v ae = *(const s8v*)(emh + (mt * 16 + c) * 64 + ksub * 32 + g * 8);
            a2[mt][0] = __builtin_amdgcn_mfma_f32_16x16x32_bf16(ae, bs[0], a2[mt][0], 0,0,0);
            a2[mt][1] = __builtin_amdgcn_mfma_f32_16x16x32_bf16(ae, bs[1], a2[mt][1], 0,0,0);
        }
    }

    unsigned short* yrow = ybf + (size_t)bh * NL;
    #pragma unroll
    for (int mt = 0; mt < 2; ++mt)
        #pragma unroll
        for (int ntl = 0; ntl < 2; ++ntl) {
            const int chunk = (2 * wv + ntl) * 16 + c;
            f4v v = a2[mt][ntl];
            float gv[4];
            #pragma unroll
            for (int r = 0; r < 4; ++r) {
                float x = v[r];
                gv[r] = 0.5f * x * (1.0f + erff(x * 0.70710678118654752f));
            }
            unsigned int lo = cvt_pk_bf16(gv[0], gv[1]);
            unsigned int hi = cvt_pk_bf16(gv[2], gv[3]);
            *(uint2*)(yrow + chunk * 32 + mt * 16 + 4 * g) = make_uint2(lo, hi);
        }
}

// ---------------- MFMA GEMM + GLU: b32 pack-in-register staging ----------------
__global__ __launch_bounds__(512) void gemm_glu_mfma(
        const unsigned short* __restrict__ ybf,
        const unsigned short* __restrict__ Wbf,
        const float* __restrict__ bo,
        float* __restrict__ out) {
    const int l0 = blockIdx.x * 64;
    const int b  = blockIdx.y;
    const int tid = threadIdx.x;
    const int lane = tid & 63;
    const int wv = tid >> 6;            // 0..7
    const int g = lane >> 4, c = lane & 15;

    __shared__ __align__(16) unsigned int ldsY[64 * 132];  // 33792 B

    // ---- stage v2: thread owns rows (2kp, 2kp+1) x 16 l; pack in reg, 16x ds_write_b32 ----
    {
        const int kp = tid >> 2;        // 0..127
        const int lq = tid & 3;         // l-quarter
        const int kps = kp ^ ((lq >> 1) << 4);   // same swizzle: hh = l/32 = lq>>1
        const unsigned short* ysrcA = ybf + ((size_t)b * NH + 2 * kp) * NL + l0 + lq * 16;
        const unsigned short* ysrcB = ysrcA + NL;
        uint4 a0 = ((const uint4*)ysrcA)[0];
        uint4 a1 = ((const uint4*)ysrcA)[1];
        uint4 b0 = ((const uint4*)ysrcB)[0];
        uint4 b1 = ((const uint4*)ysrcB)[1];
        u8h ah0 = *(const u8h*)&a0, ah1 = *(const u8h*)&a1;
        u8h bh0 = *(const u8h*)&b0, bh1 = *(const u8h*)&b1;
        const int lbase = lq * 16;
        #pragma unroll
        for (int j = 0; j < 8; ++j) {
            ldsY[(lbase + j) * 132 + kps] =
                (unsigned int)ah0[j] | ((unsigned int)bh0[j] << 16);
            ldsY[(lbase + j + 8) * 132 + kps] =
                (unsigned int)ah1[j] | ((unsigned int)bh1[j] << 16);
        }
    }
    __syncthreads();

    f4v acc[4][4];
    #pragma unroll
    for (int m = 0; m < 4; ++m)
        #pragma unroll
        for (int n = 0; n < 4; ++n)
            acc[m][n] = (f4v){0.f, 0.f, 0.f, 0.f};

    int wrow[4];
    wrow[0] = wv * 32 + c;
    wrow[1] = wrow[0] + 16;
    wrow[2] = wrow[0] + 256;
    wrow[3] = wrow[1] + 256;

    s8v afr[4];
    #pragma unroll
    for (int m = 0; m < 4; ++m)
        afr[m] = *(const s8v*)(Wbf + wrow[m] * NH + g * 8);

    #pragma unroll
    for (int ks = 0; ks < 8; ++ks) {
        s8v acur[4];
        #pragma unroll
        for (int m = 0; m < 4; ++m) acur[m] = afr[m];
        if (ks < 7) {
            #pragma unroll
            for (int m = 0; m < 4; ++m)
                afr[m] = *(const s8v*)(Wbf + wrow[m] * NH + (ks + 1) * 32 + g * 8);
        }
        s8v bfr[4];
        #pragma unroll
        for (int n = 0; n < 4; ++n) {
            const int colb = (ks * 16 + g * 4) ^ ((n >> 1) << 4);
            bfr[n] = *(const s8v*)&ldsY[(n * 16 + c) * 132 + colb];
        }
        #pragma unroll
        for (int m = 0; m < 4; ++m)
            #pragma unroll
            for (int n = 0; n < 4; ++n)
                acc[m][n] = __builtin_amdgcn_mfma_f32_16x16x32_bf16(
                    acur[m], bfr[n], acc[m][n], 0, 0, 0);
    }

    #pragma unroll
    for (int m = 0; m < 2; ++m) {
        const int o0 = wv * 32 + m * 16 + g * 4;
        float4 ba = *(const float4*)(bo + o0);
        float4 bb = *(const float4*)(bo + NH + o0);
        const float baj[4] = {ba.x, ba.y, ba.z, ba.w};
        const float bbj[4] = {bb.x, bb.y, bb.z, bb.w};
        #pragma unroll
        for (int j = 0; j < 4; ++j) {
            float* orow = out + ((size_t)(b * NH + o0 + j)) * NL + l0 + c;
            #pragma unroll
            for (int n = 0; n < 4; ++n) {
                float za = acc[m][n][j] + baj[j];
                float zb = acc[m + 2][n][j] + bbj[j];
                float s = __builtin_amdgcn_rcpf(1.0f + __expf(-zb));
                orow[n * 16] = za * s;
            }
        }
    }
}

extern "C" void kernel_launch(void* const* d_in, const int* in_sizes, int n_in,
                              void* d_out, int out_size, void* d_ws, size_t ws_size,
                              hipStream_t stream) {
    (void)in_sizes; (void)n_in; (void)out_size; (void)ws_size;
    const float* u      = (const float*)d_in[0];
    const float* log_dt = (const float*)d_in[1];
    const float* Cr     = (const float*)d_in[2];
    const float* Ci     = (const float*)d_in[3];
    const float* lar    = (const float*)d_in[4];
    const float* aim    = (const float*)d_in[5];
    const float* Dvec   = (const float*)d_in[6];
    const float* W      = (const float*)d_in[7];
    const float* bo     = (const float*)d_in[8];
    float* out = (float*)d_out;

    char* ws = (char*)d_ws;
    float*          w32c = (float*)ws;                          // 64 KB
    unsigned short* Mp   = (unsigned short*)(ws + 65536);       // 1 MB
    unsigned short* Em   = (unsigned short*)(ws + 1114112);     // 1 MB
    unsigned short* Tm   = (unsigned short*)(ws + 2162688);     // 512 KB
    unsigned short* Wbf  = (unsigned short*)(ws + 2686976);     // 256 KB
    unsigned short* ybf  = (unsigned short*)(ws + 2949120);     // 32 MB

    precompute_kernel<<<dim3(NH), dim3(64), 0, stream>>>(
        log_dt, Cr, Ci, lar, aim, Dvec, w32c, Mp, Em, Tm, W, Wbf);
    scan_mfma_kernel<<<dim3(NB * NH), dim3(256), 0, stream>>>(u, w32c, Mp, Tm, Em, ybf);
    gemm_glu_mfma<<<dim3(NL / 64, NB), dim3(512), 0, stream>>>(ybf, Wbf, bo, out);
}